// Round 1
// baseline (2164.411 us; speedup 1.0000x reference)
//
#include <hip/hip_runtime.h>
#include <hip/hip_bf16.h>
#include <math.h>

typedef __bf16 bf16_t;
typedef __bf16 bf16x8 __attribute__((ext_vector_type(8)));
typedef __bf16 bf16x4 __attribute__((ext_vector_type(4)));
typedef float f32x4 __attribute__((ext_vector_type(4)));
typedef unsigned short u16;
typedef u16 u16x8 __attribute__((ext_vector_type(8)));

#define NDEPTH 4
#define DIM 1024
#define NHEADS 16
#define MLP_DIM 4096
#define CTXD 768
#define NTOK 4096
#define NCTX 2048
#define ATT_SCALE 0.125f

__device__ inline void gload_lds16(const void* g, void* l) {
  __builtin_amdgcn_global_load_lds(
      (const __attribute__((address_space(1))) void*)g,
      (__attribute__((address_space(3))) void*)l, 16, 0, 0);
}

// ---------------- GEMM: C[M,N] = A[M,K](bf16) * Bt[N,K]^T(bf16) ----------------
// EPI: 0 = plain bf16 out; 2 = bias + exact GELU, bf16 out; 3 = bias + residual, f32 out
template<int EPI>
__global__ __launch_bounds__(256) void gemm_bf16(
    const bf16_t* __restrict__ A, const bf16_t* __restrict__ Bt,
    const float* __restrict__ bias, const float* __restrict__ res,
    void* __restrict__ outp, int M, int N, int K)
{
  __shared__ bf16_t As[2][128 * 32];
  __shared__ bf16_t Bs[2][128 * 32];
  const int tid = threadIdx.x, lane = tid & 63, wave = tid >> 6;
  const int bx = blockIdx.x, by = blockIdx.y;
  const int wr = wave >> 1, wc = wave & 1;
  const int l15 = lane & 15, l4 = lane >> 4;

  const bf16_t* Ag = A + (size_t)by * 128 * K;
  const bf16_t* Bg = Bt + (size_t)bx * 128 * K;

  f32x4 acc[4][4] = {};

  auto stage = [&](int buf, int k0) {
#pragma unroll
    for (int r = 0; r < 2; ++r) {
      int cbase = r * 256 + wave * 64;
      int c = cbase + lane;
      int row = c >> 2, off = (c & 3) * 8;
      gload_lds16(Ag + (size_t)row * K + k0 + off, &As[buf][(size_t)cbase * 8]);
      gload_lds16(Bg + (size_t)row * K + k0 + off, &Bs[buf][(size_t)cbase * 8]);
    }
  };

  const int nk = K >> 5;
  stage(0, 0);
  __syncthreads();
  for (int t = 0; t < nk; ++t) {
    const int cur = t & 1;
    if (t + 1 < nk) stage(cur ^ 1, (t + 1) << 5);
    bf16x8 af[4], bfr[4];
#pragma unroll
    for (int mi = 0; mi < 4; ++mi)
      af[mi] = *(const bf16x8*)&As[cur][(wr * 64 + mi * 16 + l15) * 32 + l4 * 8];
#pragma unroll
    for (int ni = 0; ni < 4; ++ni)
      bfr[ni] = *(const bf16x8*)&Bs[cur][(wc * 64 + ni * 16 + l15) * 32 + l4 * 8];
#pragma unroll
    for (int mi = 0; mi < 4; ++mi)
#pragma unroll
      for (int ni = 0; ni < 4; ++ni)
        acc[mi][ni] = __builtin_amdgcn_mfma_f32_16x16x32_bf16(af[mi], bfr[ni], acc[mi][ni], 0, 0, 0);
    __syncthreads();
  }

  const int r0 = by * 128 + wr * 64, c0 = bx * 128 + wc * 64;
#pragma unroll
  for (int ni = 0; ni < 4; ++ni) {
    int col = c0 + ni * 16 + l15;
    float bv = (EPI == 0) ? 0.f : bias[col];
#pragma unroll
    for (int mi = 0; mi < 4; ++mi) {
#pragma unroll
      for (int r = 0; r < 4; ++r) {
        int row = r0 + mi * 16 + l4 * 4 + r;
        float v = acc[mi][ni][r] + bv;
        size_t idx = (size_t)row * N + col;
        if (EPI == 3) {
          ((float*)outp)[idx] = v + res[idx];
        } else if (EPI == 2) {
          float gv = 0.5f * v * (1.f + erff(v * 0.70710678118f));
          ((bf16_t*)outp)[idx] = (bf16_t)gv;
        } else {
          ((bf16_t*)outp)[idx] = (bf16_t)v;
        }
      }
    }
  }
}

// ---------------- Flash attention: 64-query tile per block, d=64 ----------------
__global__ __launch_bounds__(256) void attn_fwd(
    const bf16_t* __restrict__ Q, int qs,
    const bf16_t* __restrict__ K, const bf16_t* __restrict__ V, int kvs,
    bf16_t* __restrict__ O, int os, int nq, int nk)
{
  __shared__ bf16_t Qs[64][72];
  __shared__ bf16_t Ks[64][72];
  __shared__ bf16_t Vt[64][72];       // Vt[d][key]
  __shared__ bf16_t Ps[4][16][72];    // per-wave P strip

  const int tid = threadIdx.x, lane = tid & 63, wave = tid >> 6;
  const int l15 = lane & 15, l4 = lane >> 4;
  const int h = blockIdx.y, bz = blockIdx.z;
  const size_t qrow0 = (size_t)bz * nq + (size_t)blockIdx.x * 64;
  const bf16_t* Qb = Q + qrow0 * qs + h * 64;
  const bf16_t* Kb = K + (size_t)bz * nk * kvs + h * 64;
  const bf16_t* Vb = V + (size_t)bz * nk * kvs + h * 64;
  bf16_t* Ob = O + qrow0 * os + h * 64;

#pragma unroll
  for (int it = 0; it < 2; ++it) {
    int c = it * 256 + tid;
    int row = c >> 3, col = (c & 7) * 8;
    *(u16x8*)&Qs[row][col] = *(const u16x8*)(Qb + (size_t)row * qs + col);
  }
  __syncthreads();

  bf16x8 qa[2];
#pragma unroll
  for (int ks = 0; ks < 2; ++ks)
    qa[ks] = *(const bf16x8*)&Qs[wave * 16 + l15][ks * 32 + l4 * 8];

  float m_run[4], l_run[4];
  f32x4 acc[4] = {};
#pragma unroll
  for (int r = 0; r < 4; ++r) { m_run[r] = -1e30f; l_run[r] = 0.f; }

  const int ntiles = nk >> 6;
  for (int kt = 0; kt < ntiles; ++kt) {
    __syncthreads();
#pragma unroll
    for (int it = 0; it < 2; ++it) {
      int c = it * 256 + tid;
      int row = c >> 3, col = (c & 7) * 8;
      *(u16x8*)&Ks[row][col] = *(const u16x8*)(Kb + (size_t)(kt * 64 + row) * kvs + col);
    }
#pragma unroll
    for (int it = 0; it < 2; ++it) {
      int c = it * 256 + tid;
      int d = c & 63, kb = c >> 6;  // kb in 0..7
      u16x8 tmp;
#pragma unroll
      for (int i = 0; i < 8; ++i)
        tmp[i] = *(const u16*)(Vb + (size_t)(kt * 64 + kb * 8 + i) * kvs + d);
      *(u16x8*)&Vt[d][kb * 8] = tmp;
    }
    __syncthreads();

    // S = Q K^T  (16 q-rows per wave x 64 keys)
    f32x4 s[4] = {};
#pragma unroll
    for (int ks = 0; ks < 2; ++ks) {
#pragma unroll
      for (int f = 0; f < 4; ++f) {
        bf16x8 kf = *(const bf16x8*)&Ks[f * 16 + l15][ks * 32 + l4 * 8];
        s[f] = __builtin_amdgcn_mfma_f32_16x16x32_bf16(qa[ks], kf, s[f], 0, 0, 0);
      }
    }

    float esc[4];
    float p[4][4];
#pragma unroll
    for (int r = 0; r < 4; ++r) {
      float v = fmaxf(fmaxf(s[0][r], s[1][r]), fmaxf(s[2][r], s[3][r])) * ATT_SCALE;
#pragma unroll
      for (int off = 1; off < 16; off <<= 1)
        v = fmaxf(v, __shfl_xor(v, off));
      float mn = fmaxf(m_run[r], v);
      esc[r] = __expf(m_run[r] - mn);
      m_run[r] = mn;
      float srow = 0.f;
#pragma unroll
      for (int f = 0; f < 4; ++f) {
        float pv = __expf(s[f][r] * ATT_SCALE - mn);
        p[f][r] = pv;
        srow += pv;
      }
#pragma unroll
      for (int off = 1; off < 16; off <<= 1)
        srow += __shfl_xor(srow, off);
      l_run[r] = l_run[r] * esc[r] + srow;
    }
#pragma unroll
    for (int d = 0; d < 4; ++d)
#pragma unroll
      for (int r = 0; r < 4; ++r)
        acc[d][r] *= esc[r];

    // P -> LDS (wave-private), re-fragment as MFMA A operand
#pragma unroll
    for (int f = 0; f < 4; ++f)
#pragma unroll
      for (int r = 0; r < 4; ++r)
        Ps[wave][l4 * 4 + r][f * 16 + l15] = (bf16_t)p[f][r];

#pragma unroll
    for (int ks = 0; ks < 2; ++ks) {
      bf16x8 pa = *(const bf16x8*)&Ps[wave][l15][ks * 32 + l4 * 8];
#pragma unroll
      for (int d = 0; d < 4; ++d) {
        bf16x8 vb = *(const bf16x8*)&Vt[d * 16 + l15][ks * 32 + l4 * 8];
        acc[d] = __builtin_amdgcn_mfma_f32_16x16x32_bf16(pa, vb, acc[d], 0, 0, 0);
      }
    }
  }

#pragma unroll
  for (int d = 0; d < 4; ++d) {
#pragma unroll
    for (int r = 0; r < 4; ++r) {
      int row = wave * 16 + l4 * 4 + r;
      float v = acc[d][r] / l_run[r];
      Ob[(size_t)row * os + d * 16 + l15] = (bf16_t)v;
    }
  }
}

// ---------------- LayerNorm: fp32 in, bf16 out, dim=1024 ----------------
__global__ __launch_bounds__(256) void layernorm_f32_bf16(
    const float* __restrict__ x, const float* __restrict__ g, const float* __restrict__ b,
    bf16_t* __restrict__ out)
{
  const int row = blockIdx.x, tid = threadIdx.x;
  const float4 v = ((const float4*)(x + (size_t)row * 1024))[tid];
  float s = v.x + v.y + v.z + v.w;
  float s2 = v.x * v.x + v.y * v.y + v.z * v.z + v.w * v.w;
#pragma unroll
  for (int off = 32; off > 0; off >>= 1) {
    s += __shfl_down(s, off);
    s2 += __shfl_down(s2, off);
  }
  __shared__ float ps[4], ps2[4];
  const int lane = tid & 63, wave = tid >> 6;
  if (lane == 0) { ps[wave] = s; ps2[wave] = s2; }
  __syncthreads();
  s = ps[0] + ps[1] + ps[2] + ps[3];
  s2 = ps2[0] + ps2[1] + ps2[2] + ps2[3];
  const float mu = s * (1.f / 1024.f);
  const float var = s2 * (1.f / 1024.f) - mu * mu;
  const float rstd = rsqrtf(var + 1e-5f);
  const float4 gv = ((const float4*)g)[tid];
  const float4 bv = ((const float4*)b)[tid];
  bf16x4 o;
  o[0] = (bf16_t)((v.x - mu) * rstd * gv.x + bv.x);
  o[1] = (bf16_t)((v.y - mu) * rstd * gv.y + bv.y);
  o[2] = (bf16_t)((v.z - mu) * rstd * gv.z + bv.z);
  o[3] = (bf16_t)((v.w - mu) * rstd * gv.w + bv.w);
  *(bf16x4*)(out + (size_t)row * 1024 + tid * 4) = o;
}

// ---------------- weight transpose fp32[K,N] -> bf16[N,K], per-layer in grid.z ----------------
__global__ void transpose_to_bf16(const float* __restrict__ src, bf16_t* __restrict__ dst, int K, int N)
{
  __shared__ float tile[32][33];
  const size_t loff = (size_t)blockIdx.z * K * N;
  src += loff; dst += loff;
  const int k0 = blockIdx.y * 32, n0 = blockIdx.x * 32;
  const int tx = threadIdx.x, ty = threadIdx.y;
#pragma unroll
  for (int i = ty; i < 32; i += 8)
    tile[i][tx] = src[(size_t)(k0 + i) * N + n0 + tx];
  __syncthreads();
#pragma unroll
  for (int i = ty; i < 32; i += 8)
    dst[(size_t)(n0 + i) * K + k0 + tx] = (bf16_t)tile[tx][i];
}

__global__ void f32_to_bf16(const float* __restrict__ src, bf16_t* __restrict__ dst, int n4)
{
  int i = blockIdx.x * blockDim.x + threadIdx.x;
  if (i < n4) {
    float4 v = ((const float4*)src)[i];
    bf16x4 o;
    o[0] = (bf16_t)v.x; o[1] = (bf16_t)v.y; o[2] = (bf16_t)v.z; o[3] = (bf16_t)v.w;
    ((bf16x4*)dst)[i] = o;
  }
}

__global__ void copy_f32(const float* __restrict__ src, float* __restrict__ dst, int n4)
{
  int i = blockIdx.x * blockDim.x + threadIdx.x;
  if (i < n4) ((float4*)dst)[i] = ((const float4*)src)[i];
}

extern "C" void kernel_launch(void* const* d_in, const int* in_sizes, int n_in,
                              void* d_out, int out_size, void* d_ws, size_t ws_size,
                              hipStream_t stream)
{
  const float* x      = (const float*)d_in[0];
  const float* ctx    = (const float*)d_in[1];
  const float* ln1_g  = (const float*)d_in[2];
  const float* ln1_b  = (const float*)d_in[3];
  const float* w_qkv  = (const float*)d_in[4];
  const float* w_sa_o = (const float*)d_in[5];
  const float* b_sa_o = (const float*)d_in[6];
  const float* ln2_g  = (const float*)d_in[7];
  const float* ln2_b  = (const float*)d_in[8];
  const float* w_q    = (const float*)d_in[9];
  const float* w_kv   = (const float*)d_in[10];
  const float* w_ca_o = (const float*)d_in[11];
  const float* b_ca_o = (const float*)d_in[12];
  const float* ln3_g  = (const float*)d_in[13];
  const float* ln3_b  = (const float*)d_in[14];
  const float* w_ff1  = (const float*)d_in[15];
  const float* b_ff1  = (const float*)d_in[16];
  const float* w_ff2  = (const float*)d_in[17];
  const float* b_ff2  = (const float*)d_in[18];

  char* p = (char*)d_ws;
  auto alloc = [&](size_t bytes) { char* r = p; p += (bytes + 255) & ~(size_t)255; return r; };
  bf16_t* wqkv_t = (bf16_t*)alloc((size_t)NDEPTH * 3072 * 1024 * 2);
  bf16_t* wsao_t = (bf16_t*)alloc((size_t)NDEPTH * 1024 * 1024 * 2);
  bf16_t* wq_t   = (bf16_t*)alloc((size_t)NDEPTH * 1024 * 1024 * 2);
  bf16_t* wkv_t  = (bf16_t*)alloc((size_t)NDEPTH * 2048 * 768 * 2);
  bf16_t* wcao_t = (bf16_t*)alloc((size_t)NDEPTH * 1024 * 1024 * 2);
  bf16_t* wff1_t = (bf16_t*)alloc((size_t)NDEPTH * 4096 * 1024 * 2);
  bf16_t* wff2_t = (bf16_t*)alloc((size_t)NDEPTH * 1024 * 4096 * 2);
  bf16_t* ctxb   = (bf16_t*)alloc((size_t)NCTX * CTXD * 2);
  float*  xbuf   = (float*)alloc((size_t)NTOK * DIM * 4);
  bf16_t* lnbuf  = (bf16_t*)alloc((size_t)NTOK * DIM * 2);    // also attention out
  bf16_t* bigbuf = (bf16_t*)alloc((size_t)NTOK * 4096 * 2);   // qkv / ff1 out
  bf16_t* qbuf   = (bf16_t*)alloc((size_t)NTOK * DIM * 2);
  bf16_t* kvbuf  = (bf16_t*)alloc((size_t)NCTX * 2048 * 2);
  if ((size_t)(p - (char*)d_ws) > ws_size) return;  // workspace too small: fail loudly

  dim3 tb(32, 8);
  transpose_to_bf16<<<dim3(3072 / 32, 1024 / 32, NDEPTH), tb, 0, stream>>>(w_qkv, wqkv_t, 1024, 3072);
  transpose_to_bf16<<<dim3(1024 / 32, 1024 / 32, NDEPTH), tb, 0, stream>>>(w_sa_o, wsao_t, 1024, 1024);
  transpose_to_bf16<<<dim3(1024 / 32, 1024 / 32, NDEPTH), tb, 0, stream>>>(w_q, wq_t, 1024, 1024);
  transpose_to_bf16<<<dim3(2048 / 32, 768 / 32, NDEPTH), tb, 0, stream>>>(w_kv, wkv_t, 768, 2048);
  transpose_to_bf16<<<dim3(1024 / 32, 1024 / 32, NDEPTH), tb, 0, stream>>>(w_ca_o, wcao_t, 1024, 1024);
  transpose_to_bf16<<<dim3(4096 / 32, 1024 / 32, NDEPTH), tb, 0, stream>>>(w_ff1, wff1_t, 1024, 4096);
  transpose_to_bf16<<<dim3(1024 / 32, 4096 / 32, NDEPTH), tb, 0, stream>>>(w_ff2, wff2_t, 4096, 1024);
  f32_to_bf16<<<(NCTX * CTXD / 4 + 255) / 256, 256, 0, stream>>>(ctx, ctxb, NCTX * CTXD / 4);
  copy_f32<<<(NTOK * DIM / 4 + 255) / 256, 256, 0, stream>>>(x, xbuf, NTOK * DIM / 4);

  for (int i = 0; i < NDEPTH; ++i) {
    // ---- self-attention ----
    layernorm_f32_bf16<<<NTOK, 256, 0, stream>>>(xbuf, ln1_g + i * DIM, ln1_b + i * DIM, lnbuf);
    gemm_bf16<0><<<dim3(3072 / 128, NTOK / 128), 256, 0, stream>>>(
        lnbuf, wqkv_t + (size_t)i * 3072 * 1024, nullptr, nullptr, bigbuf, NTOK, 3072, 1024);
    attn_fwd<<<dim3(2048 / 64, NHEADS, 2), 256, 0, stream>>>(
        bigbuf, 3072, bigbuf + 1024, bigbuf + 2048, 3072, lnbuf, 1024, 2048, 2048);
    gemm_bf16<3><<<dim3(1024 / 128, NTOK / 128), 256, 0, stream>>>(
        lnbuf, wsao_t + (size_t)i * 1024 * 1024, b_sa_o + i * DIM, xbuf, xbuf, NTOK, 1024, 1024);
    // ---- cross-attention ----
    layernorm_f32_bf16<<<NTOK, 256, 0, stream>>>(xbuf, ln2_g + i * DIM, ln2_b + i * DIM, lnbuf);
    gemm_bf16<0><<<dim3(1024 / 128, NTOK / 128), 256, 0, stream>>>(
        lnbuf, wq_t + (size_t)i * 1024 * 1024, nullptr, nullptr, qbuf, NTOK, 1024, 1024);
    gemm_bf16<0><<<dim3(2048 / 128, NCTX / 128), 256, 0, stream>>>(
        ctxb, wkv_t + (size_t)i * 2048 * 768, nullptr, nullptr, kvbuf, NCTX, 2048, 768);
    attn_fwd<<<dim3(2048 / 64, NHEADS, 2), 256, 0, stream>>>(
        qbuf, 1024, kvbuf, kvbuf + 1024, 2048, lnbuf, 1024, 2048, 1024);
    gemm_bf16<3><<<dim3(1024 / 128, NTOK / 128), 256, 0, stream>>>(
        lnbuf, wcao_t + (size_t)i * 1024 * 1024, b_ca_o + i * DIM, xbuf, xbuf, NTOK, 1024, 1024);
    // ---- feed-forward ----
    layernorm_f32_bf16<<<NTOK, 256, 0, stream>>>(xbuf, ln3_g + i * DIM, ln3_b + i * DIM, lnbuf);
    gemm_bf16<2><<<dim3(4096 / 128, NTOK / 128), 256, 0, stream>>>(
        lnbuf, wff1_t + (size_t)i * 4096 * 1024, b_ff1 + i * MLP_DIM, nullptr, bigbuf, NTOK, 4096, 1024);
    gemm_bf16<3><<<dim3(1024 / 128, NTOK / 128), 256, 0, stream>>>(
        bigbuf, wff2_t + (size_t)i * 1024 * 4096, b_ff2 + i * DIM, xbuf, xbuf, NTOK, 1024, 4096);
  }
  copy_f32<<<(NTOK * DIM / 4 + 255) / 256, 256, 0, stream>>>(xbuf, (float*)d_out, NTOK * DIM / 4);
}

// Round 2
// 1936.313 us; speedup vs baseline: 1.1178x; 1.1178x over previous
//
#include <hip/hip_runtime.h>
#include <hip/hip_bf16.h>
#include <math.h>

typedef __bf16 bf16_t;
typedef __bf16 bf16x8 __attribute__((ext_vector_type(8)));
typedef __bf16 bf16x4 __attribute__((ext_vector_type(4)));
typedef float f32x4 __attribute__((ext_vector_type(4)));
typedef unsigned short u16;
typedef u16 u16x8 __attribute__((ext_vector_type(8)));

#define NDEPTH 4
#define DIM 1024
#define NHEADS 16
#define MLP_DIM 4096
#define CTXD 768
#define NTOK 4096
#define NCTX 2048
#define ATT_SCALE 0.125f

__device__ inline void gload_lds16(const void* g, void* l) {
  __builtin_amdgcn_global_load_lds(
      (const __attribute__((address_space(1))) void*)g,
      (__attribute__((address_space(3))) void*)l, 16, 0, 0);
}

// ---------------- GEMM: C[M,N] = A[M,K](bf16) * Bt[N,K]^T(bf16) ----------------
// EPI: 0 = plain bf16 out; 2 = bias + exact GELU, bf16 out; 3 = bias + residual, f32 out
template<int EPI>
__global__ __launch_bounds__(256) void gemm_bf16(
    const bf16_t* __restrict__ A, const bf16_t* __restrict__ Bt,
    const float* __restrict__ bias, const float* __restrict__ res,
    void* __restrict__ outp, int M, int N, int K)
{
  __shared__ bf16_t As[2][128 * 32];
  __shared__ bf16_t Bs[2][128 * 32];
  const int tid = threadIdx.x, lane = tid & 63, wave = tid >> 6;
  const int bx = blockIdx.x, by = blockIdx.y;
  const int wr = wave >> 1, wc = wave & 1;
  const int l15 = lane & 15, l4 = lane >> 4;

  const bf16_t* Ag = A + (size_t)by * 128 * K;
  const bf16_t* Bg = Bt + (size_t)bx * 128 * K;

  f32x4 acc[4][4] = {};

  auto stage = [&](int buf, int k0) {
#pragma unroll
    for (int r = 0; r < 2; ++r) {
      int cbase = r * 256 + wave * 64;
      int c = cbase + lane;
      int row = c >> 2, off = (c & 3) * 8;
      gload_lds16(Ag + (size_t)row * K + k0 + off, &As[buf][(size_t)cbase * 8]);
      gload_lds16(Bg + (size_t)row * K + k0 + off, &Bs[buf][(size_t)cbase * 8]);
    }
  };

  const int nk = K >> 5;
  stage(0, 0);
  __syncthreads();
  for (int t = 0; t < nk; ++t) {
    const int cur = t & 1;
    if (t + 1 < nk) stage(cur ^ 1, (t + 1) << 5);
    bf16x8 af[4], bfr[4];
#pragma unroll
    for (int mi = 0; mi < 4; ++mi)
      af[mi] = *(const bf16x8*)&As[cur][(wr * 64 + mi * 16 + l15) * 32 + l4 * 8];
#pragma unroll
    for (int ni = 0; ni < 4; ++ni)
      bfr[ni] = *(const bf16x8*)&Bs[cur][(wc * 64 + ni * 16 + l15) * 32 + l4 * 8];
#pragma unroll
    for (int mi = 0; mi < 4; ++mi)
#pragma unroll
      for (int ni = 0; ni < 4; ++ni)
        acc[mi][ni] = __builtin_amdgcn_mfma_f32_16x16x32_bf16(af[mi], bfr[ni], acc[mi][ni], 0, 0, 0);
    __syncthreads();
  }

  const int r0 = by * 128 + wr * 64, c0 = bx * 128 + wc * 64;
#pragma unroll
  for (int ni = 0; ni < 4; ++ni) {
    int col = c0 + ni * 16 + l15;
    float bv = (EPI == 0) ? 0.f : bias[col];
#pragma unroll
    for (int mi = 0; mi < 4; ++mi) {
#pragma unroll
      for (int r = 0; r < 4; ++r) {
        int row = r0 + mi * 16 + l4 * 4 + r;
        float v = acc[mi][ni][r] + bv;
        size_t idx = (size_t)row * N + col;
        if (EPI == 3) {
          ((float*)outp)[idx] = v + res[idx];
        } else if (EPI == 2) {
          float gv = 0.5f * v * (1.f + erff(v * 0.70710678118f));
          ((bf16_t*)outp)[idx] = (bf16_t)gv;
        } else {
          ((bf16_t*)outp)[idx] = (bf16_t)v;
        }
      }
    }
  }
}

// ---------------- Flash attention: 128-query tile, 8 waves, d=64 ----------------
// T14 async-stage: load tile t+1 K/V to regs before compute, write LDS after.
// One barrier per tile via double-buffered K/V LDS. Q in registers.
// Row-sum via MFMA with ones B-operand (no shuffle-sum).
__global__ __launch_bounds__(512) void attn_fwd(
    const bf16_t* __restrict__ Q, int qs,
    const bf16_t* __restrict__ K, const bf16_t* __restrict__ V, int kvs,
    bf16_t* __restrict__ O, int os, int nq, int nk)
{
  __shared__ bf16_t Ks[2][64][72];
  __shared__ bf16_t Vt[2][64][72];   // Vt[d][key]
  __shared__ bf16_t Ps[8][16][72];   // per-wave P strip

  const int tid = threadIdx.x, lane = tid & 63, wv = tid >> 6;
  const int l15 = lane & 15, l4 = lane >> 4;
  const int h = blockIdx.y, bz = blockIdx.z;
  const size_t qrow0 = (size_t)bz * nq + (size_t)blockIdx.x * 128;
  const bf16_t* Qb = Q + (qrow0 + wv * 16) * qs + h * 64;
  const bf16_t* Kb = K + (size_t)bz * nk * kvs + h * 64;
  const bf16_t* Vb = V + (size_t)bz * nk * kvs + h * 64;
  bf16_t* Ob = O + (qrow0 + wv * 16) * os + h * 64;

  // Q fragments straight from global (one-time)
  bf16x8 qa[2];
#pragma unroll
  for (int ks = 0; ks < 2; ++ks)
    qa[ks] = *(const bf16x8*)(Qb + (size_t)l15 * qs + ks * 32 + l4 * 8);

  const int krow = tid >> 3, kcol = (tid & 7) * 8;

  u16x8 kreg, vreg;
  auto load_tile = [&](int kt) {
    kreg = *(const u16x8*)(Kb + (size_t)(kt * 64 + krow) * kvs + kcol);
    u16x8 t;
#pragma unroll
    for (int i = 0; i < 8; ++i)
      t[i] = *(const u16*)(Vb + (size_t)(kt * 64 + wv * 8 + i) * kvs + lane);
    vreg = t;
  };
  auto store_tile = [&](int buf) {
    *(u16x8*)&Ks[buf][krow][kcol] = kreg;
    *(u16x8*)&Vt[buf][lane][wv * 8] = vreg;
  };

  float m_run[4];
  f32x4 acc[4] = {};
  f32x4 acc1 = {};   // running row-sum (denominator), same layout as acc
#pragma unroll
  for (int r = 0; r < 4; ++r) m_run[r] = -1e30f;

  const bf16_t onev = (bf16_t)1.0f;
  const bf16x8 vones = {onev, onev, onev, onev, onev, onev, onev, onev};

  const int ntiles = nk >> 6;
  load_tile(0);
  store_tile(0);
  __syncthreads();

  for (int kt = 0; kt < ntiles; ++kt) {
    const int cur = kt & 1;
    const bool pre = (kt + 1 < ntiles);
    if (pre) load_tile(kt + 1);   // overlaps with everything below

    // S = Q K^T : lane holds S[q = wv*16 + l4*4 + r][key = f*16 + l15]
    f32x4 s[4] = {};
#pragma unroll
    for (int ks = 0; ks < 2; ++ks)
#pragma unroll
      for (int f = 0; f < 4; ++f) {
        bf16x8 kf = *(const bf16x8*)&Ks[cur][f * 16 + l15][ks * 32 + l4 * 8];
        s[f] = __builtin_amdgcn_mfma_f32_16x16x32_bf16(qa[ks], kf, s[f], 0, 0, 0);
      }

    float esc[4], p[4][4];
#pragma unroll
    for (int r = 0; r < 4; ++r) {
      float v = fmaxf(fmaxf(s[0][r], s[1][r]), fmaxf(s[2][r], s[3][r]));
#pragma unroll
      for (int off = 1; off < 16; off <<= 1)
        v = fmaxf(v, __shfl_xor(v, off));
      v *= ATT_SCALE;
      float mn = fmaxf(m_run[r], v);
      esc[r] = __expf(m_run[r] - mn);
      m_run[r] = mn;
#pragma unroll
      for (int f = 0; f < 4; ++f)
        p[f][r] = __expf(s[f][r] * ATT_SCALE - mn);
    }
#pragma unroll
    for (int r = 0; r < 4; ++r) {
      acc1[r] *= esc[r];
#pragma unroll
      for (int d = 0; d < 4; ++d) acc[d][r] *= esc[r];
    }

    // P -> wave-private LDS strip, re-fragment as MFMA A operand
#pragma unroll
    for (int f = 0; f < 4; ++f)
#pragma unroll
      for (int r = 0; r < 4; ++r)
        Ps[wv][l4 * 4 + r][f * 16 + l15] = (bf16_t)p[f][r];

#pragma unroll
    for (int ks = 0; ks < 2; ++ks) {
      bf16x8 pa = *(const bf16x8*)&Ps[wv][l15][ks * 32 + l4 * 8];
      acc1 = __builtin_amdgcn_mfma_f32_16x16x32_bf16(pa, vones, acc1, 0, 0, 0);
#pragma unroll
      for (int d = 0; d < 4; ++d) {
        bf16x8 vb = *(const bf16x8*)&Vt[cur][d * 16 + l15][ks * 32 + l4 * 8];
        acc[d] = __builtin_amdgcn_mfma_f32_16x16x32_bf16(pa, vb, acc[d], 0, 0, 0);
      }
    }

    if (pre) store_tile(cur ^ 1);  // regs -> other LDS buffer; loads done by now
    __syncthreads();
  }

#pragma unroll
  for (int r = 0; r < 4; ++r) {
    float inv = 1.f / acc1[r];
#pragma unroll
    for (int d = 0; d < 4; ++d)
      Ob[(size_t)(l4 * 4 + r) * os + d * 16 + l15] = (bf16_t)(acc[d][r] * inv);
  }
}

// ---------------- LayerNorm: fp32 in, bf16 out, dim=1024 ----------------
__global__ __launch_bounds__(256) void layernorm_f32_bf16(
    const float* __restrict__ x, const float* __restrict__ g, const float* __restrict__ b,
    bf16_t* __restrict__ out)
{
  const int row = blockIdx.x, tid = threadIdx.x;
  const float4 v = ((const float4*)(x + (size_t)row * 1024))[tid];
  float s = v.x + v.y + v.z + v.w;
  float s2 = v.x * v.x + v.y * v.y + v.z * v.z + v.w * v.w;
#pragma unroll
  for (int off = 32; off > 0; off >>= 1) {
    s += __shfl_down(s, off);
    s2 += __shfl_down(s2, off);
  }
  __shared__ float ps[4], ps2[4];
  const int lane = tid & 63, wave = tid >> 6;
  if (lane == 0) { ps[wave] = s; ps2[wave] = s2; }
  __syncthreads();
  s = ps[0] + ps[1] + ps[2] + ps[3];
  s2 = ps2[0] + ps2[1] + ps2[2] + ps2[3];
  const float mu = s * (1.f / 1024.f);
  const float var = s2 * (1.f / 1024.f) - mu * mu;
  const float rstd = rsqrtf(var + 1e-5f);
  const float4 gv = ((const float4*)g)[tid];
  const float4 bv = ((const float4*)b)[tid];
  bf16x4 o;
  o[0] = (bf16_t)((v.x - mu) * rstd * gv.x + bv.x);
  o[1] = (bf16_t)((v.y - mu) * rstd * gv.y + bv.y);
  o[2] = (bf16_t)((v.z - mu) * rstd * gv.z + bv.z);
  o[3] = (bf16_t)((v.w - mu) * rstd * gv.w + bv.w);
  *(bf16x4*)(out + (size_t)row * 1024 + tid * 4) = o;
}

// ---------------- weight transpose fp32[K,N] -> bf16[N,K], per-layer in grid.z ----------------
__global__ void transpose_to_bf16(const float* __restrict__ src, bf16_t* __restrict__ dst, int K, int N)
{
  __shared__ float tile[32][33];
  const size_t loff = (size_t)blockIdx.z * K * N;
  src += loff; dst += loff;
  const int k0 = blockIdx.y * 32, n0 = blockIdx.x * 32;
  const int tx = threadIdx.x, ty = threadIdx.y;
#pragma unroll
  for (int i = ty; i < 32; i += 8)
    tile[i][tx] = src[(size_t)(k0 + i) * N + n0 + tx];
  __syncthreads();
#pragma unroll
  for (int i = ty; i < 32; i += 8)
    dst[(size_t)(n0 + i) * K + k0 + tx] = (bf16_t)tile[tx][i];
}

__global__ void f32_to_bf16(const float* __restrict__ src, bf16_t* __restrict__ dst, int n4)
{
  int i = blockIdx.x * blockDim.x + threadIdx.x;
  if (i < n4) {
    float4 v = ((const float4*)src)[i];
    bf16x4 o;
    o[0] = (bf16_t)v.x; o[1] = (bf16_t)v.y; o[2] = (bf16_t)v.z; o[3] = (bf16_t)v.w;
    ((bf16x4*)dst)[i] = o;
  }
}

__global__ void copy_f32(const float* __restrict__ src, float* __restrict__ dst, int n4)
{
  int i = blockIdx.x * blockDim.x + threadIdx.x;
  if (i < n4) ((float4*)dst)[i] = ((const float4*)src)[i];
}

extern "C" void kernel_launch(void* const* d_in, const int* in_sizes, int n_in,
                              void* d_out, int out_size, void* d_ws, size_t ws_size,
                              hipStream_t stream)
{
  const float* x      = (const float*)d_in[0];
  const float* ctx    = (const float*)d_in[1];
  const float* ln1_g  = (const float*)d_in[2];
  const float* ln1_b  = (const float*)d_in[3];
  const float* w_qkv  = (const float*)d_in[4];
  const float* w_sa_o = (const float*)d_in[5];
  const float* b_sa_o = (const float*)d_in[6];
  const float* ln2_g  = (const float*)d_in[7];
  const float* ln2_b  = (const float*)d_in[8];
  const float* w_q    = (const float*)d_in[9];
  const float* w_kv   = (const float*)d_in[10];
  const float* w_ca_o = (const float*)d_in[11];
  const float* b_ca_o = (const float*)d_in[12];
  const float* ln3_g  = (const float*)d_in[13];
  const float* ln3_b  = (const float*)d_in[14];
  const float* w_ff1  = (const float*)d_in[15];
  const float* b_ff1  = (const float*)d_in[16];
  const float* w_ff2  = (const float*)d_in[17];
  const float* b_ff2  = (const float*)d_in[18];

  char* p = (char*)d_ws;
  auto alloc = [&](size_t bytes) { char* r = p; p += (bytes + 255) & ~(size_t)255; return r; };
  bf16_t* wqkv_t = (bf16_t*)alloc((size_t)NDEPTH * 3072 * 1024 * 2);
  bf16_t* wsao_t = (bf16_t*)alloc((size_t)NDEPTH * 1024 * 1024 * 2);
  bf16_t* wq_t   = (bf16_t*)alloc((size_t)NDEPTH * 1024 * 1024 * 2);
  bf16_t* wkv_t  = (bf16_t*)alloc((size_t)NDEPTH * 2048 * 768 * 2);
  bf16_t* wcao_t = (bf16_t*)alloc((size_t)NDEPTH * 1024 * 1024 * 2);
  bf16_t* wff1_t = (bf16_t*)alloc((size_t)NDEPTH * 4096 * 1024 * 2);
  bf16_t* wff2_t = (bf16_t*)alloc((size_t)NDEPTH * 1024 * 4096 * 2);
  bf16_t* ctxb   = (bf16_t*)alloc((size_t)NCTX * CTXD * 2);
  float*  xbuf   = (float*)alloc((size_t)NTOK * DIM * 4);
  bf16_t* lnbuf  = (bf16_t*)alloc((size_t)NTOK * DIM * 2);    // also attention out
  bf16_t* bigbuf = (bf16_t*)alloc((size_t)NTOK * 4096 * 2);   // qkv / ff1 out
  bf16_t* qbuf   = (bf16_t*)alloc((size_t)NTOK * DIM * 2);
  bf16_t* kvbuf  = (bf16_t*)alloc((size_t)NCTX * 2048 * 2);
  if ((size_t)(p - (char*)d_ws) > ws_size) return;  // workspace too small: fail loudly

  dim3 tb(32, 8);
  transpose_to_bf16<<<dim3(3072 / 32, 1024 / 32, NDEPTH), tb, 0, stream>>>(w_qkv, wqkv_t, 1024, 3072);
  transpose_to_bf16<<<dim3(1024 / 32, 1024 / 32, NDEPTH), tb, 0, stream>>>(w_sa_o, wsao_t, 1024, 1024);
  transpose_to_bf16<<<dim3(1024 / 32, 1024 / 32, NDEPTH), tb, 0, stream>>>(w_q, wq_t, 1024, 1024);
  transpose_to_bf16<<<dim3(2048 / 32, 768 / 32, NDEPTH), tb, 0, stream>>>(w_kv, wkv_t, 768, 2048);
  transpose_to_bf16<<<dim3(1024 / 32, 1024 / 32, NDEPTH), tb, 0, stream>>>(w_ca_o, wcao_t, 1024, 1024);
  transpose_to_bf16<<<dim3(4096 / 32, 1024 / 32, NDEPTH), tb, 0, stream>>>(w_ff1, wff1_t, 1024, 4096);
  transpose_to_bf16<<<dim3(1024 / 32, 4096 / 32, NDEPTH), tb, 0, stream>>>(w_ff2, wff2_t, 4096, 1024);
  f32_to_bf16<<<(NCTX * CTXD / 4 + 255) / 256, 256, 0, stream>>>(ctx, ctxb, NCTX * CTXD / 4);
  copy_f32<<<(NTOK * DIM / 4 + 255) / 256, 256, 0, stream>>>(x, xbuf, NTOK * DIM / 4);

  for (int i = 0; i < NDEPTH; ++i) {
    // ---- self-attention ----
    layernorm_f32_bf16<<<NTOK, 256, 0, stream>>>(xbuf, ln1_g + i * DIM, ln1_b + i * DIM, lnbuf);
    gemm_bf16<0><<<dim3(3072 / 128, NTOK / 128), 256, 0, stream>>>(
        lnbuf, wqkv_t + (size_t)i * 3072 * 1024, nullptr, nullptr, bigbuf, NTOK, 3072, 1024);
    attn_fwd<<<dim3(2048 / 128, NHEADS, 2), 512, 0, stream>>>(
        bigbuf, 3072, bigbuf + 1024, bigbuf + 2048, 3072, lnbuf, 1024, 2048, 2048);
    gemm_bf16<3><<<dim3(1024 / 128, NTOK / 128), 256, 0, stream>>>(
        lnbuf, wsao_t + (size_t)i * 1024 * 1024, b_sa_o + i * DIM, xbuf, xbuf, NTOK, 1024, 1024);
    // ---- cross-attention ----
    layernorm_f32_bf16<<<NTOK, 256, 0, stream>>>(xbuf, ln2_g + i * DIM, ln2_b + i * DIM, lnbuf);
    gemm_bf16<0><<<dim3(1024 / 128, NTOK / 128), 256, 0, stream>>>(
        lnbuf, wq_t + (size_t)i * 1024 * 1024, nullptr, nullptr, qbuf, NTOK, 1024, 1024);
    gemm_bf16<0><<<dim3(2048 / 128, NCTX / 128), 256, 0, stream>>>(
        ctxb, wkv_t + (size_t)i * 2048 * 768, nullptr, nullptr, kvbuf, NCTX, 2048, 768);
    attn_fwd<<<dim3(2048 / 128, NHEADS, 2), 512, 0, stream>>>(
        qbuf, 1024, kvbuf, kvbuf + 1024, 2048, lnbuf, 1024, 2048, 1024);
    gemm_bf16<3><<<dim3(1024 / 128, NTOK / 128), 256, 0, stream>>>(
        lnbuf, wcao_t + (size_t)i * 1024 * 1024, b_ca_o + i * DIM, xbuf, xbuf, NTOK, 1024, 1024);
    // ---- feed-forward ----
    layernorm_f32_bf16<<<NTOK, 256, 0, stream>>>(xbuf, ln3_g + i * DIM, ln3_b + i * DIM, lnbuf);
    gemm_bf16<2><<<dim3(4096 / 128, NTOK / 128), 256, 0, stream>>>(
        lnbuf, wff1_t + (size_t)i * 4096 * 1024, b_ff1 + i * MLP_DIM, nullptr, bigbuf, NTOK, 4096, 1024);
    gemm_bf16<3><<<dim3(1024 / 128, NTOK / 128), 256, 0, stream>>>(
        bigbuf, wff2_t + (size_t)i * 1024 * 4096, b_ff2 + i * DIM, xbuf, xbuf, NTOK, 1024, 4096);
  }
  copy_f32<<<(NTOK * DIM / 4 + 255) / 256, 256, 0, stream>>>(xbuf, (float*)d_out, NTOK * DIM / 4);
}

// Round 3
// 1932.568 us; speedup vs baseline: 1.1200x; 1.0019x over previous
//
#include <hip/hip_runtime.h>
#include <hip/hip_bf16.h>
#include <math.h>

typedef __bf16 bf16_t;
typedef __bf16 bf16x8 __attribute__((ext_vector_type(8)));
typedef __bf16 bf16x4 __attribute__((ext_vector_type(4)));
typedef float f32x4 __attribute__((ext_vector_type(4)));
typedef unsigned short u16;
typedef unsigned int u32;
typedef u16 u16x8 __attribute__((ext_vector_type(8)));

#define NDEPTH 4
#define DIM 1024
#define NHEADS 16
#define MLP_DIM 4096
#define CTXD 768
#define NTOK 4096
#define NCTX 2048
#define ATT_SCALE 0.125f

__device__ inline void gload_lds16(const void* g, void* l) {
  __builtin_amdgcn_global_load_lds(
      (const __attribute__((address_space(1))) void*)g,
      (__attribute__((address_space(3))) void*)l, 16, 0, 0);
}

__device__ inline u32 packbf2(float a, float b) {
  union { bf16_t h[2]; u32 w; } u;
  u.h[0] = (bf16_t)a; u.h[1] = (bf16_t)b;
  return u.w;
}

// ---------------- GEMM: C[M,N] = A[M,K](bf16) * Bt[N,K]^T(bf16) ----------------
// EPI: 0 = plain bf16 out; 2 = bias + exact GELU, bf16 out; 3 = bias + residual, f32 out
template<int EPI>
__global__ __launch_bounds__(256) void gemm_bf16(
    const bf16_t* __restrict__ A, const bf16_t* __restrict__ Bt,
    const float* __restrict__ bias, const float* __restrict__ res,
    void* __restrict__ outp, int M, int N, int K)
{
  __shared__ bf16_t As[2][128 * 32];
  __shared__ bf16_t Bs[2][128 * 32];
  const int tid = threadIdx.x, lane = tid & 63, wave = tid >> 6;
  const int bx = blockIdx.x, by = blockIdx.y;
  const int wr = wave >> 1, wc = wave & 1;
  const int l15 = lane & 15, l4 = lane >> 4;

  const bf16_t* Ag = A + (size_t)by * 128 * K;
  const bf16_t* Bg = Bt + (size_t)bx * 128 * K;

  f32x4 acc[4][4] = {};

  auto stage = [&](int buf, int k0) {
#pragma unroll
    for (int r = 0; r < 2; ++r) {
      int cbase = r * 256 + wave * 64;
      int c = cbase + lane;
      int row = c >> 2, off = (c & 3) * 8;
      gload_lds16(Ag + (size_t)row * K + k0 + off, &As[buf][(size_t)cbase * 8]);
      gload_lds16(Bg + (size_t)row * K + k0 + off, &Bs[buf][(size_t)cbase * 8]);
    }
  };

  const int nk = K >> 5;
  stage(0, 0);
  __syncthreads();
  for (int t = 0; t < nk; ++t) {
    const int cur = t & 1;
    if (t + 1 < nk) stage(cur ^ 1, (t + 1) << 5);
    bf16x8 af[4], bfr[4];
#pragma unroll
    for (int mi = 0; mi < 4; ++mi)
      af[mi] = *(const bf16x8*)&As[cur][(wr * 64 + mi * 16 + l15) * 32 + l4 * 8];
#pragma unroll
    for (int ni = 0; ni < 4; ++ni)
      bfr[ni] = *(const bf16x8*)&Bs[cur][(wc * 64 + ni * 16 + l15) * 32 + l4 * 8];
#pragma unroll
    for (int mi = 0; mi < 4; ++mi)
#pragma unroll
      for (int ni = 0; ni < 4; ++ni)
        acc[mi][ni] = __builtin_amdgcn_mfma_f32_16x16x32_bf16(af[mi], bfr[ni], acc[mi][ni], 0, 0, 0);
    __syncthreads();
  }

  const int r0 = by * 128 + wr * 64, c0 = bx * 128 + wc * 64;
#pragma unroll
  for (int ni = 0; ni < 4; ++ni) {
    int col = c0 + ni * 16 + l15;
    float bv = (EPI == 0) ? 0.f : bias[col];
#pragma unroll
    for (int mi = 0; mi < 4; ++mi) {
#pragma unroll
      for (int r = 0; r < 4; ++r) {
        int row = r0 + mi * 16 + l4 * 4 + r;
        float v = acc[mi][ni][r] + bv;
        size_t idx = (size_t)row * N + col;
        if (EPI == 3) {
          ((float*)outp)[idx] = v + res[idx];
        } else if (EPI == 2) {
          float gv = 0.5f * v * (1.f + erff(v * 0.70710678118f));
          ((bf16_t*)outp)[idx] = (bf16_t)gv;
        } else {
          ((bf16_t*)outp)[idx] = (bf16_t)v;
        }
      }
    }
  }
}

// ---------------- Flash attention: 128-query tile, 8 waves, d=64 ----------------
// Swapped QK^T (mfma(K,Q)) -> each lane holds S[16 keys][q=l15]: softmax is
// in-lane + 2 shfl_xor. P stays in registers; redistribution to the PV
// A-fragment layout via 16 ds_bpermute (conflict-free) + selects. No P LDS.
// T14 async-stage for K/V, double-buffered, one barrier per tile.
__global__ __launch_bounds__(512) void attn_fwd(
    const bf16_t* __restrict__ Q, int qs,
    const bf16_t* __restrict__ K, const bf16_t* __restrict__ V, int kvs,
    bf16_t* __restrict__ O, int os, int nq, int nk)
{
  __shared__ bf16_t Ks[2][64][72];
  __shared__ bf16_t Vt[2][64][72];   // Vt[d][key]

  const int tid = threadIdx.x, lane = tid & 63, wv = tid >> 6;
  const int l15 = lane & 15, l4 = lane >> 4;
  const int h = blockIdx.y, bz = blockIdx.z;
  const size_t qrow0 = (size_t)bz * nq + (size_t)blockIdx.x * 128;
  const bf16_t* Qb = Q + (qrow0 + wv * 16) * qs + h * 64;
  const bf16_t* Kb = K + (size_t)bz * nk * kvs + h * 64;
  const bf16_t* Vb = V + (size_t)bz * nk * kvs + h * 64;
  bf16_t* Ob = O + (qrow0 + wv * 16) * os + h * 64;

  // Q as MFMA B-operand: lane holds Q[q=l15][k = ks*32 + l4*8 + j]
  bf16x8 qa[2];
#pragma unroll
  for (int ks = 0; ks < 2; ++ks)
    qa[ks] = *(const bf16x8*)(Qb + (size_t)l15 * qs + ks * 32 + l4 * 8);

  const int krow = tid >> 3, kcol = (tid & 7) * 8;

  u16x8 kreg, vreg;
  auto load_tile = [&](int kt) {
    kreg = *(const u16x8*)(Kb + (size_t)(kt * 64 + krow) * kvs + kcol);
    u16x8 t;
#pragma unroll
    for (int i = 0; i < 8; ++i)
      t[i] = *(const u16*)(Vb + (size_t)(kt * 64 + wv * 8 + i) * kvs + lane);
    vreg = t;
  };
  auto store_tile = [&](int buf) {
    *(u16x8*)&Ks[buf][krow][kcol] = kreg;
    *(u16x8*)&Vt[buf][lane][wv * 8] = vreg;
  };

  float m_run = -1e30f, l_run = 0.f;  // stats for q-row = l15
  f32x4 acc[4] = {};                  // acc[d0][r] = O[q=l4*4+r][d=d0*16+l15]

  const int ntiles = nk >> 6;
  load_tile(0);
  store_tile(0);
  __syncthreads();

  for (int kt = 0; kt < ntiles; ++kt) {
    const int cur = kt & 1;
    const bool pre = (kt + 1 < ntiles);
    if (pre) load_tile(kt + 1);   // HBM latency hides under compute below

    // S^T: s[f] holds S[key = f*16 + l4*4 + r][q = l15]
    f32x4 s[4] = {};
#pragma unroll
    for (int ks = 0; ks < 2; ++ks)
#pragma unroll
      for (int f = 0; f < 4; ++f) {
        bf16x8 kf = *(const bf16x8*)&Ks[cur][f * 16 + l15][ks * 32 + l4 * 8];
        s[f] = __builtin_amdgcn_mfma_f32_16x16x32_bf16(kf, qa[ks], s[f], 0, 0, 0);
      }

    // in-lane row stats over 16 keys, then combine the 4 sibling lanes
    float smax = s[0][0];
#pragma unroll
    for (int f = 0; f < 4; ++f)
#pragma unroll
      for (int r = 0; r < 4; ++r) smax = fmaxf(smax, s[f][r]);
    smax = fmaxf(smax, __shfl_xor(smax, 16));
    smax = fmaxf(smax, __shfl_xor(smax, 32));
    smax *= ATT_SCALE;
    const float mn = fmaxf(m_run, smax);
    const float esc = __expf(m_run - mn);
    m_run = mn;

    float p[4][4], psum = 0.f;
#pragma unroll
    for (int f = 0; f < 4; ++f)
#pragma unroll
      for (int r = 0; r < 4; ++r) {
        float pv = __expf(s[f][r] * ATT_SCALE - mn);
        p[f][r] = pv;
        psum += pv;
      }
    psum += __shfl_xor(psum, 16);
    psum += __shfl_xor(psum, 32);
    l_run = l_run * esc + psum;

    // rescale acc with per-q esc (q = l4*4 + r, held by lane l4*16 + l4*4 + r)
#pragma unroll
    for (int r = 0; r < 4; ++r) {
      float eq = __shfl(esc, (l4 << 4) + (l4 << 2) + r);
#pragma unroll
      for (int d0 = 0; d0 < 4; ++d0) acc[d0][r] *= eq;
    }

    // pack P to bf16 pairs: pk[f][h] = P[key = f*16+l4*4+2h .. +1][q=l15]
    u32 pk[4][2];
#pragma unroll
    for (int f = 0; f < 4; ++f)
#pragma unroll
      for (int hh = 0; hh < 2; ++hh)
        pk[f][hh] = packbf2(p[f][2 * hh], p[f][2 * hh + 1]);

    // redistribute to PV A-fragment: pa[ks] = P[q=l15][key = ks*32 + l4*8 + j]
    bf16x8 pa[2];
#pragma unroll
    for (int ks = 0; ks < 2; ++ks) {
      union { u32 w[4]; bf16x8 v; } pu;
#pragma unroll
      for (int jj = 0; jj < 4; ++jj) {
        int src = l15 + ((((l4 << 1) + (jj >> 1)) & 3) << 4);
        u32 a = (u32)__shfl((int)pk[ks * 2 + 0][jj & 1], src);
        u32 b = (u32)__shfl((int)pk[ks * 2 + 1][jj & 1], src);
        pu.w[jj] = (l4 & 2) ? b : a;
      }
      pa[ks] = pu.v;
    }

    // O += P V : A = pa (rows=q), B = Vt rows (V^T[d][key])
#pragma unroll
    for (int ks = 0; ks < 2; ++ks)
#pragma unroll
      for (int d0 = 0; d0 < 4; ++d0) {
        bf16x8 vb = *(const bf16x8*)&Vt[cur][d0 * 16 + l15][ks * 32 + l4 * 8];
        acc[d0] = __builtin_amdgcn_mfma_f32_16x16x32_bf16(pa[ks], vb, acc[d0], 0, 0, 0);
      }

    if (pre) store_tile(cur ^ 1);
    __syncthreads();
  }

#pragma unroll
  for (int r = 0; r < 4; ++r) {
    float lq = __shfl(l_run, (l4 << 4) + (l4 << 2) + r);
    float inv = 1.f / lq;
#pragma unroll
    for (int d0 = 0; d0 < 4; ++d0)
      Ob[(size_t)(l4 * 4 + r) * os + d0 * 16 + l15] = (bf16_t)(acc[d0][r] * inv);
  }
}

// ---------------- LayerNorm: fp32 in, bf16 out, dim=1024 ----------------
__global__ __launch_bounds__(256) void layernorm_f32_bf16(
    const float* __restrict__ x, const float* __restrict__ g, const float* __restrict__ b,
    bf16_t* __restrict__ out)
{
  const int row = blockIdx.x, tid = threadIdx.x;
  const float4 v = ((const float4*)(x + (size_t)row * 1024))[tid];
  float s = v.x + v.y + v.z + v.w;
  float s2 = v.x * v.x + v.y * v.y + v.z * v.z + v.w * v.w;
#pragma unroll
  for (int off = 32; off > 0; off >>= 1) {
    s += __shfl_down(s, off);
    s2 += __shfl_down(s2, off);
  }
  __shared__ float ps[4], ps2[4];
  const int lane = tid & 63, wave = tid >> 6;
  if (lane == 0) { ps[wave] = s; ps2[wave] = s2; }
  __syncthreads();
  s = ps[0] + ps[1] + ps[2] + ps[3];
  s2 = ps2[0] + ps2[1] + ps2[2] + ps2[3];
  const float mu = s * (1.f / 1024.f);
  const float var = s2 * (1.f / 1024.f) - mu * mu;
  const float rstd = rsqrtf(var + 1e-5f);
  const float4 gv = ((const float4*)g)[tid];
  const float4 bv = ((const float4*)b)[tid];
  bf16x4 o;
  o[0] = (bf16_t)((v.x - mu) * rstd * gv.x + bv.x);
  o[1] = (bf16_t)((v.y - mu) * rstd * gv.y + bv.y);
  o[2] = (bf16_t)((v.z - mu) * rstd * gv.z + bv.z);
  o[3] = (bf16_t)((v.w - mu) * rstd * gv.w + bv.w);
  *(bf16x4*)(out + (size_t)row * 1024 + tid * 4) = o;
}

// ---------------- weight transpose fp32[K,N] -> bf16[N,K], per-layer in grid.z ----------------
__global__ void transpose_to_bf16(const float* __restrict__ src, bf16_t* __restrict__ dst, int K, int N)
{
  __shared__ float tile[32][33];
  const size_t loff = (size_t)blockIdx.z * K * N;
  src += loff; dst += loff;
  const int k0 = blockIdx.y * 32, n0 = blockIdx.x * 32;
  const int tx = threadIdx.x, ty = threadIdx.y;
#pragma unroll
  for (int i = ty; i < 32; i += 8)
    tile[i][tx] = src[(size_t)(k0 + i) * N + n0 + tx];
  __syncthreads();
#pragma unroll
  for (int i = ty; i < 32; i += 8)
    dst[(size_t)(n0 + i) * K + k0 + tx] = (bf16_t)tile[tx][i];
}

__global__ void f32_to_bf16(const float* __restrict__ src, bf16_t* __restrict__ dst, int n4)
{
  int i = blockIdx.x * blockDim.x + threadIdx.x;
  if (i < n4) {
    float4 v = ((const float4*)src)[i];
    bf16x4 o;
    o[0] = (bf16_t)v.x; o[1] = (bf16_t)v.y; o[2] = (bf16_t)v.z; o[3] = (bf16_t)v.w;
    ((bf16x4*)dst)[i] = o;
  }
}

__global__ void copy_f32(const float* __restrict__ src, float* __restrict__ dst, int n4)
{
  int i = blockIdx.x * blockDim.x + threadIdx.x;
  if (i < n4) ((float4*)dst)[i] = ((const float4*)src)[i];
}

extern "C" void kernel_launch(void* const* d_in, const int* in_sizes, int n_in,
                              void* d_out, int out_size, void* d_ws, size_t ws_size,
                              hipStream_t stream)
{
  const float* x      = (const float*)d_in[0];
  const float* ctx    = (const float*)d_in[1];
  const float* ln1_g  = (const float*)d_in[2];
  const float* ln1_b  = (const float*)d_in[3];
  const float* w_qkv  = (const float*)d_in[4];
  const float* w_sa_o = (const float*)d_in[5];
  const float* b_sa_o = (const float*)d_in[6];
  const float* ln2_g  = (const float*)d_in[7];
  const float* ln2_b  = (const float*)d_in[8];
  const float* w_q    = (const float*)d_in[9];
  const float* w_kv   = (const float*)d_in[10];
  const float* w_ca_o = (const float*)d_in[11];
  const float* b_ca_o = (const float*)d_in[12];
  const float* ln3_g  = (const float*)d_in[13];
  const float* ln3_b  = (const float*)d_in[14];
  const float* w_ff1  = (const float*)d_in[15];
  const float* b_ff1  = (const float*)d_in[16];
  const float* w_ff2  = (const float*)d_in[17];
  const float* b_ff2  = (const float*)d_in[18];

  char* p = (char*)d_ws;
  auto alloc = [&](size_t bytes) { char* r = p; p += (bytes + 255) & ~(size_t)255; return r; };
  bf16_t* wqkv_t = (bf16_t*)alloc((size_t)NDEPTH * 3072 * 1024 * 2);
  bf16_t* wsao_t = (bf16_t*)alloc((size_t)NDEPTH * 1024 * 1024 * 2);
  bf16_t* wq_t   = (bf16_t*)alloc((size_t)NDEPTH * 1024 * 1024 * 2);
  bf16_t* wkv_t  = (bf16_t*)alloc((size_t)NDEPTH * 2048 * 768 * 2);
  bf16_t* wcao_t = (bf16_t*)alloc((size_t)NDEPTH * 1024 * 1024 * 2);
  bf16_t* wff1_t = (bf16_t*)alloc((size_t)NDEPTH * 4096 * 1024 * 2);
  bf16_t* wff2_t = (bf16_t*)alloc((size_t)NDEPTH * 1024 * 4096 * 2);
  bf16_t* ctxb   = (bf16_t*)alloc((size_t)NCTX * CTXD * 2);
  float*  xbuf   = (float*)alloc((size_t)NTOK * DIM * 4);
  bf16_t* lnbuf  = (bf16_t*)alloc((size_t)NTOK * DIM * 2);    // also attention out
  bf16_t* bigbuf = (bf16_t*)alloc((size_t)NTOK * 4096 * 2);   // qkv / ff1 out
  bf16_t* qbuf   = (bf16_t*)alloc((size_t)NTOK * DIM * 2);
  bf16_t* kvbuf  = (bf16_t*)alloc((size_t)NCTX * 2048 * 2);
  if ((size_t)(p - (char*)d_ws) > ws_size) return;  // workspace too small: fail loudly

  dim3 tb(32, 8);
  transpose_to_bf16<<<dim3(3072 / 32, 1024 / 32, NDEPTH), tb, 0, stream>>>(w_qkv, wqkv_t, 1024, 3072);
  transpose_to_bf16<<<dim3(1024 / 32, 1024 / 32, NDEPTH), tb, 0, stream>>>(w_sa_o, wsao_t, 1024, 1024);
  transpose_to_bf16<<<dim3(1024 / 32, 1024 / 32, NDEPTH), tb, 0, stream>>>(w_q, wq_t, 1024, 1024);
  transpose_to_bf16<<<dim3(2048 / 32, 768 / 32, NDEPTH), tb, 0, stream>>>(w_kv, wkv_t, 768, 2048);
  transpose_to_bf16<<<dim3(1024 / 32, 1024 / 32, NDEPTH), tb, 0, stream>>>(w_ca_o, wcao_t, 1024, 1024);
  transpose_to_bf16<<<dim3(4096 / 32, 1024 / 32, NDEPTH), tb, 0, stream>>>(w_ff1, wff1_t, 1024, 4096);
  transpose_to_bf16<<<dim3(1024 / 32, 4096 / 32, NDEPTH), tb, 0, stream>>>(w_ff2, wff2_t, 4096, 1024);
  f32_to_bf16<<<(NCTX * CTXD / 4 + 255) / 256, 256, 0, stream>>>(ctx, ctxb, NCTX * CTXD / 4);
  copy_f32<<<(NTOK * DIM / 4 + 255) / 256, 256, 0, stream>>>(x, xbuf, NTOK * DIM / 4);

  for (int i = 0; i < NDEPTH; ++i) {
    // ---- self-attention ----
    layernorm_f32_bf16<<<NTOK, 256, 0, stream>>>(xbuf, ln1_g + i * DIM, ln1_b + i * DIM, lnbuf);
    gemm_bf16<0><<<dim3(3072 / 128, NTOK / 128), 256, 0, stream>>>(
        lnbuf, wqkv_t + (size_t)i * 3072 * 1024, nullptr, nullptr, bigbuf, NTOK, 3072, 1024);
    attn_fwd<<<dim3(2048 / 128, NHEADS, 2), 512, 0, stream>>>(
        bigbuf, 3072, bigbuf + 1024, bigbuf + 2048, 3072, lnbuf, 1024, 2048, 2048);
    gemm_bf16<3><<<dim3(1024 / 128, NTOK / 128), 256, 0, stream>>>(
        lnbuf, wsao_t + (size_t)i * 1024 * 1024, b_sa_o + i * DIM, xbuf, xbuf, NTOK, 1024, 1024);
    // ---- cross-attention ----
    layernorm_f32_bf16<<<NTOK, 256, 0, stream>>>(xbuf, ln2_g + i * DIM, ln2_b + i * DIM, lnbuf);
    gemm_bf16<0><<<dim3(1024 / 128, NTOK / 128), 256, 0, stream>>>(
        lnbuf, wq_t + (size_t)i * 1024 * 1024, nullptr, nullptr, qbuf, NTOK, 1024, 1024);
    gemm_bf16<0><<<dim3(2048 / 128, NCTX / 128), 256, 0, stream>>>(
        ctxb, wkv_t + (size_t)i * 2048 * 768, nullptr, nullptr, kvbuf, NCTX, 2048, 768);
    attn_fwd<<<dim3(2048 / 128, NHEADS, 2), 512, 0, stream>>>(
        qbuf, 1024, kvbuf, kvbuf + 1024, 2048, lnbuf, 1024, 2048, 1024);
    gemm_bf16<3><<<dim3(1024 / 128, NTOK / 128), 256, 0, stream>>>(
        lnbuf, wcao_t + (size_t)i * 1024 * 1024, b_ca_o + i * DIM, xbuf, xbuf, NTOK, 1024, 1024);
    // ---- feed-forward ----
    layernorm_f32_bf16<<<NTOK, 256, 0, stream>>>(xbuf, ln3_g + i * DIM, ln3_b + i * DIM, lnbuf);
    gemm_bf16<2><<<dim3(4096 / 128, NTOK / 128), 256, 0, stream>>>(
        lnbuf, wff1_t + (size_t)i * 4096 * 1024, b_ff1 + i * MLP_DIM, nullptr, bigbuf, NTOK, 4096, 1024);
    gemm_bf16<3><<<dim3(1024 / 128, NTOK / 128), 256, 0, stream>>>(
        bigbuf, wff2_t + (size_t)i * 1024 * 4096, b_ff2 + i * DIM, xbuf, xbuf, NTOK, 1024, 4096);
  }
  copy_f32<<<(NTOK * DIM / 4 + 255) / 256, 256, 0, stream>>>(xbuf, (float*)d_out, NTOK * DIM / 4);
}

// Round 4
// 1863.927 us; speedup vs baseline: 1.1612x; 1.0368x over previous
//
#include <hip/hip_runtime.h>
#include <hip/hip_bf16.h>
#include <math.h>

typedef __bf16 bf16_t;
typedef __bf16 bf16x8 __attribute__((ext_vector_type(8)));
typedef __bf16 bf16x4 __attribute__((ext_vector_type(4)));
typedef float f32x4 __attribute__((ext_vector_type(4)));
typedef unsigned short u16;
typedef unsigned int u32;
typedef u16 u16x8 __attribute__((ext_vector_type(8)));

#define NDEPTH 4
#define DIM 1024
#define NHEADS 16
#define MLP_DIM 4096
#define CTXD 768
#define NTOK 4096
#define NCTX 2048
#define ATT_SCALE 0.125f

__device__ inline void gload_lds16(const void* g, void* l) {
  __builtin_amdgcn_global_load_lds(
      (const __attribute__((address_space(1))) void*)g,
      (__attribute__((address_space(3))) void*)l, 16, 0, 0);
}

__device__ inline u32 packbf2(float a, float b) {
  union { bf16_t h[2]; u32 w; } u;
  u.h[0] = (bf16_t)a; u.h[1] = (bf16_t)b;
  return u.w;
}

// ---------------- GEMM: C[M,N] = A[M,K](bf16) * Bt[N,K]^T(bf16) ----------------
// 8 waves (2M x 4N), per-wave 64x32 out. 3-buffer LDS pipeline, 2-deep
// prefetch with counted vmcnt + raw s_barrier (T3/T4 minimum recipe):
// loads never drain to 0 in the main loop, so single-block/CU shapes
// (N=1024 GEMMs, grid=256) don't expose the stage latency.
// EPI: 0 = plain bf16 out; 2 = bias + exact GELU, bf16 out; 3 = bias + residual, f32 out
template<int EPI>
__global__ __launch_bounds__(512) void gemm_bf16(
    const bf16_t* __restrict__ A, const bf16_t* __restrict__ Bt,
    const float* __restrict__ bias, const float* __restrict__ res,
    void* __restrict__ outp, int M, int N, int K)
{
  __shared__ alignas(16) bf16_t As[3][128 * 32];
  __shared__ alignas(16) bf16_t Bs[3][128 * 32];
  const int tid = threadIdx.x, lane = tid & 63, wave = tid >> 6;
  const int bx = blockIdx.x, by = blockIdx.y;
  const int wr = wave >> 2, wc = wave & 3;      // 2 x 4 wave grid
  const int l15 = lane & 15, l4 = lane >> 4;

  const bf16_t* Ag = A + (size_t)by * 128 * K;
  const bf16_t* Bg = Bt + (size_t)bx * 128 * K;

  f32x4 acc[4][2] = {};

  // 512 threads stage one 128x32 tile of A and of B: 1x16B each.
  const int srow = tid >> 2, soff = (tid & 3) * 8;
  auto stage = [&](int buf, int k0) {
    gload_lds16(Ag + (size_t)srow * K + k0 + soff, &As[buf][(size_t)tid * 8]);
    gload_lds16(Bg + (size_t)srow * K + k0 + soff, &Bs[buf][(size_t)tid * 8]);
  };

  const int nk = K >> 5;   // BK = 32, nk >= 2 for all shapes here
  stage(0, 0);
  stage(1, 32);
  asm volatile("s_waitcnt vmcnt(2)" ::: "memory");   // stage(0) complete
  __builtin_amdgcn_s_barrier();
  __builtin_amdgcn_sched_barrier(0);

  for (int t = 0; t < nk; ++t) {
    const int cur = t % 3;
    if (t + 2 < nk) stage((t + 2) % 3, (t + 2) << 5);   // 2-deep prefetch

    bf16x8 af[4], bfr[2];
#pragma unroll
    for (int mi = 0; mi < 4; ++mi)
      af[mi] = *(const bf16x8*)&As[cur][(wr * 64 + mi * 16 + l15) * 32 + l4 * 8];
#pragma unroll
    for (int ni = 0; ni < 2; ++ni)
      bfr[ni] = *(const bf16x8*)&Bs[cur][(wc * 32 + ni * 16 + l15) * 32 + l4 * 8];
#pragma unroll
    for (int mi = 0; mi < 4; ++mi)
#pragma unroll
      for (int ni = 0; ni < 2; ++ni)
        acc[mi][ni] = __builtin_amdgcn_mfma_f32_16x16x32_bf16(af[mi], bfr[ni], acc[mi][ni], 0, 0, 0);

    if (t + 2 < nk) {
      asm volatile("s_waitcnt vmcnt(2)" ::: "memory");  // next buf staged; deepest 2 still in flight
    } else if (t + 1 < nk) {
      asm volatile("s_waitcnt vmcnt(0)" ::: "memory");  // tail: only stage(nk-1) outstanding
    } else {
      break;                                            // last tile: no barrier needed
    }
    __builtin_amdgcn_s_barrier();
    __builtin_amdgcn_sched_barrier(0);
  }

  const int r0 = by * 128 + wr * 64, c0 = bx * 128 + wc * 32;
#pragma unroll
  for (int ni = 0; ni < 2; ++ni) {
    int col = c0 + ni * 16 + l15;
    float bv = (EPI == 0) ? 0.f : bias[col];
#pragma unroll
    for (int mi = 0; mi < 4; ++mi) {
#pragma unroll
      for (int r = 0; r < 4; ++r) {
        int row = r0 + mi * 16 + l4 * 4 + r;
        float v = acc[mi][ni][r] + bv;
        size_t idx = (size_t)row * N + col;
        if (EPI == 3) {
          ((float*)outp)[idx] = v + res[idx];
        } else if (EPI == 2) {
          float gv = 0.5f * v * (1.f + erff(v * 0.70710678118f));
          ((bf16_t*)outp)[idx] = (bf16_t)gv;
        } else {
          ((bf16_t*)outp)[idx] = (bf16_t)v;
        }
      }
    }
  }
}

// ---------------- Flash attention: 128-query tile, 8 waves, d=64 ----------------
// Swapped QK^T (mfma(K,Q)) -> each lane holds S[16 keys][q=l15]: softmax is
// in-lane + 2 shfl_xor. P stays in registers; redistribution to the PV
// A-fragment layout via shfl + selects. No P LDS.
// T14 async-stage for K/V, double-buffered, one barrier per tile.
__global__ __launch_bounds__(512) void attn_fwd(
    const bf16_t* __restrict__ Q, int qs,
    const bf16_t* __restrict__ K, const bf16_t* __restrict__ V, int kvs,
    bf16_t* __restrict__ O, int os, int nq, int nk)
{
  __shared__ bf16_t Ks[2][64][72];
  __shared__ bf16_t Vt[2][64][72];   // Vt[d][key]

  const int tid = threadIdx.x, lane = tid & 63, wv = tid >> 6;
  const int l15 = lane & 15, l4 = lane >> 4;
  const int h = blockIdx.y, bz = blockIdx.z;
  const size_t qrow0 = (size_t)bz * nq + (size_t)blockIdx.x * 128;
  const bf16_t* Qb = Q + (qrow0 + wv * 16) * qs + h * 64;
  const bf16_t* Kb = K + (size_t)bz * nk * kvs + h * 64;
  const bf16_t* Vb = V + (size_t)bz * nk * kvs + h * 64;
  bf16_t* Ob = O + (qrow0 + wv * 16) * os + h * 64;

  // Q as MFMA B-operand: lane holds Q[q=l15][k = ks*32 + l4*8 + j]
  bf16x8 qa[2];
#pragma unroll
  for (int ks = 0; ks < 2; ++ks)
    qa[ks] = *(const bf16x8*)(Qb + (size_t)l15 * qs + ks * 32 + l4 * 8);

  const int krow = tid >> 3, kcol = (tid & 7) * 8;

  u16x8 kreg, vreg;
  auto load_tile = [&](int kt) {
    kreg = *(const u16x8*)(Kb + (size_t)(kt * 64 + krow) * kvs + kcol);
    u16x8 t;
#pragma unroll
    for (int i = 0; i < 8; ++i)
      t[i] = *(const u16*)(Vb + (size_t)(kt * 64 + wv * 8 + i) * kvs + lane);
    vreg = t;
  };
  auto store_tile = [&](int buf) {
    *(u16x8*)&Ks[buf][krow][kcol] = kreg;
    *(u16x8*)&Vt[buf][lane][wv * 8] = vreg;
  };

  float m_run = -1e30f, l_run = 0.f;  // stats for q-row = l15
  f32x4 acc[4] = {};                  // acc[d0][r] = O[q=l4*4+r][d=d0*16+l15]

  const int ntiles = nk >> 6;
  load_tile(0);
  store_tile(0);
  __syncthreads();

  for (int kt = 0; kt < ntiles; ++kt) {
    const int cur = kt & 1;
    const bool pre = (kt + 1 < ntiles);
    if (pre) load_tile(kt + 1);   // HBM latency hides under compute below

    // S^T: s[f] holds S[key = f*16 + l4*4 + r][q = l15]
    f32x4 s[4] = {};
#pragma unroll
    for (int ks = 0; ks < 2; ++ks)
#pragma unroll
      for (int f = 0; f < 4; ++f) {
        bf16x8 kf = *(const bf16x8*)&Ks[cur][f * 16 + l15][ks * 32 + l4 * 8];
        s[f] = __builtin_amdgcn_mfma_f32_16x16x32_bf16(kf, qa[ks], s[f], 0, 0, 0);
      }

    // in-lane row stats over 16 keys, then combine the 4 sibling lanes
    float smax = s[0][0];
#pragma unroll
    for (int f = 0; f < 4; ++f)
#pragma unroll
      for (int r = 0; r < 4; ++r) smax = fmaxf(smax, s[f][r]);
    smax = fmaxf(smax, __shfl_xor(smax, 16));
    smax = fmaxf(smax, __shfl_xor(smax, 32));
    smax *= ATT_SCALE;
    const float mn = fmaxf(m_run, smax);
    const float esc = __expf(m_run - mn);
    m_run = mn;

    float p[4][4], psum = 0.f;
#pragma unroll
    for (int f = 0; f < 4; ++f)
#pragma unroll
      for (int r = 0; r < 4; ++r) {
        float pv = __expf(s[f][r] * ATT_SCALE - mn);
        p[f][r] = pv;
        psum += pv;
      }
    psum += __shfl_xor(psum, 16);
    psum += __shfl_xor(psum, 32);
    l_run = l_run * esc + psum;

    // rescale acc with per-q esc (q = l4*4 + r, held by lane l4*16 + l4*4 + r)
#pragma unroll
    for (int r = 0; r < 4; ++r) {
      float eq = __shfl(esc, (l4 << 4) + (l4 << 2) + r);
#pragma unroll
      for (int d0 = 0; d0 < 4; ++d0) acc[d0][r] *= eq;
    }

    // pack P to bf16 pairs: pk[f][h] = P[key = f*16+l4*4+2h .. +1][q=l15]
    u32 pk[4][2];
#pragma unroll
    for (int f = 0; f < 4; ++f)
#pragma unroll
      for (int hh = 0; hh < 2; ++hh)
        pk[f][hh] = packbf2(p[f][2 * hh], p[f][2 * hh + 1]);

    // redistribute to PV A-fragment: pa[ks] = P[q=l15][key = ks*32 + l4*8 + j]
    bf16x8 pa[2];
#pragma unroll
    for (int ks = 0; ks < 2; ++ks) {
      union { u32 w[4]; bf16x8 v; } pu;
#pragma unroll
      for (int jj = 0; jj < 4; ++jj) {
        int src = l15 + ((((l4 << 1) + (jj >> 1)) & 3) << 4);
        u32 a = (u32)__shfl((int)pk[ks * 2 + 0][jj & 1], src);
        u32 b = (u32)__shfl((int)pk[ks * 2 + 1][jj & 1], src);
        pu.w[jj] = (l4 & 2) ? b : a;
      }
      pa[ks] = pu.v;
    }

    // O += P V : A = pa (rows=q), B = Vt rows (V^T[d][key])
#pragma unroll
    for (int ks = 0; ks < 2; ++ks)
#pragma unroll
      for (int d0 = 0; d0 < 4; ++d0) {
        bf16x8 vb = *(const bf16x8*)&Vt[cur][d0 * 16 + l15][ks * 32 + l4 * 8];
        acc[d0] = __builtin_amdgcn_mfma_f32_16x16x32_bf16(pa[ks], vb, acc[d0], 0, 0, 0);
      }

    if (pre) store_tile(cur ^ 1);
    __syncthreads();
  }

#pragma unroll
  for (int r = 0; r < 4; ++r) {
    float lq = __shfl(l_run, (l4 << 4) + (l4 << 2) + r);
    float inv = 1.f / lq;
#pragma unroll
    for (int d0 = 0; d0 < 4; ++d0)
      Ob[(size_t)(l4 * 4 + r) * os + d0 * 16 + l15] = (bf16_t)(acc[d0][r] * inv);
  }
}

// ---------------- LayerNorm: fp32 in, bf16 out, dim=1024 ----------------
__global__ __launch_bounds__(256) void layernorm_f32_bf16(
    const float* __restrict__ x, const float* __restrict__ g, const float* __restrict__ b,
    bf16_t* __restrict__ out)
{
  const int row = blockIdx.x, tid = threadIdx.x;
  const float4 v = ((const float4*)(x + (size_t)row * 1024))[tid];
  float s = v.x + v.y + v.z + v.w;
  float s2 = v.x * v.x + v.y * v.y + v.z * v.z + v.w * v.w;
#pragma unroll
  for (int off = 32; off > 0; off >>= 1) {
    s += __shfl_down(s, off);
    s2 += __shfl_down(s2, off);
  }
  __shared__ float ps[4], ps2[4];
  const int lane = tid & 63, wave = tid >> 6;
  if (lane == 0) { ps[wave] = s; ps2[wave] = s2; }
  __syncthreads();
  s = ps[0] + ps[1] + ps[2] + ps[3];
  s2 = ps2[0] + ps2[1] + ps2[2] + ps2[3];
  const float mu = s * (1.f / 1024.f);
  const float var = s2 * (1.f / 1024.f) - mu * mu;
  const float rstd = rsqrtf(var + 1e-5f);
  const float4 gv = ((const float4*)g)[tid];
  const float4 bv = ((const float4*)b)[tid];
  bf16x4 o;
  o[0] = (bf16_t)((v.x - mu) * rstd * gv.x + bv.x);
  o[1] = (bf16_t)((v.y - mu) * rstd * gv.y + bv.y);
  o[2] = (bf16_t)((v.z - mu) * rstd * gv.z + bv.z);
  o[3] = (bf16_t)((v.w - mu) * rstd * gv.w + bv.w);
  *(bf16x4*)(out + (size_t)row * 1024 + tid * 4) = o;
}

// ---------------- weight transpose fp32[K,N] -> bf16[N,K], per-layer in grid.z ----------------
__global__ void transpose_to_bf16(const float* __restrict__ src, bf16_t* __restrict__ dst, int K, int N)
{
  __shared__ float tile[32][33];
  const size_t loff = (size_t)blockIdx.z * K * N;
  src += loff; dst += loff;
  const int k0 = blockIdx.y * 32, n0 = blockIdx.x * 32;
  const int tx = threadIdx.x, ty = threadIdx.y;
#pragma unroll
  for (int i = ty; i < 32; i += 8)
    tile[i][tx] = src[(size_t)(k0 + i) * N + n0 + tx];
  __syncthreads();
#pragma unroll
  for (int i = ty; i < 32; i += 8)
    dst[(size_t)(n0 + i) * K + k0 + tx] = (bf16_t)tile[tx][i];
}

__global__ void f32_to_bf16(const float* __restrict__ src, bf16_t* __restrict__ dst, int n4)
{
  int i = blockIdx.x * blockDim.x + threadIdx.x;
  if (i < n4) {
    float4 v = ((const float4*)src)[i];
    bf16x4 o;
    o[0] = (bf16_t)v.x; o[1] = (bf16_t)v.y; o[2] = (bf16_t)v.z; o[3] = (bf16_t)v.w;
    ((bf16x4*)dst)[i] = o;
  }
}

__global__ void copy_f32(const float* __restrict__ src, float* __restrict__ dst, int n4)
{
  int i = blockIdx.x * blockDim.x + threadIdx.x;
  if (i < n4) ((float4*)dst)[i] = ((const float4*)src)[i];
}

extern "C" void kernel_launch(void* const* d_in, const int* in_sizes, int n_in,
                              void* d_out, int out_size, void* d_ws, size_t ws_size,
                              hipStream_t stream)
{
  const float* x      = (const float*)d_in[0];
  const float* ctx    = (const float*)d_in[1];
  const float* ln1_g  = (const float*)d_in[2];
  const float* ln1_b  = (const float*)d_in[3];
  const float* w_qkv  = (const float*)d_in[4];
  const float* w_sa_o = (const float*)d_in[5];
  const float* b_sa_o = (const float*)d_in[6];
  const float* ln2_g  = (const float*)d_in[7];
  const float* ln2_b  = (const float*)d_in[8];
  const float* w_q    = (const float*)d_in[9];
  const float* w_kv   = (const float*)d_in[10];
  const float* w_ca_o = (const float*)d_in[11];
  const float* b_ca_o = (const float*)d_in[12];
  const float* ln3_g  = (const float*)d_in[13];
  const float* ln3_b  = (const float*)d_in[14];
  const float* w_ff1  = (const float*)d_in[15];
  const float* b_ff1  = (const float*)d_in[16];
  const float* w_ff2  = (const float*)d_in[17];
  const float* b_ff2  = (const float*)d_in[18];

  char* p = (char*)d_ws;
  auto alloc = [&](size_t bytes) { char* r = p; p += (bytes + 255) & ~(size_t)255; return r; };
  bf16_t* wqkv_t = (bf16_t*)alloc((size_t)NDEPTH * 3072 * 1024 * 2);
  bf16_t* wsao_t = (bf16_t*)alloc((size_t)NDEPTH * 1024 * 1024 * 2);
  bf16_t* wq_t   = (bf16_t*)alloc((size_t)NDEPTH * 1024 * 1024 * 2);
  bf16_t* wkv_t  = (bf16_t*)alloc((size_t)NDEPTH * 2048 * 768 * 2);
  bf16_t* wcao_t = (bf16_t*)alloc((size_t)NDEPTH * 1024 * 1024 * 2);
  bf16_t* wff1_t = (bf16_t*)alloc((size_t)NDEPTH * 4096 * 1024 * 2);
  bf16_t* wff2_t = (bf16_t*)alloc((size_t)NDEPTH * 1024 * 4096 * 2);
  bf16_t* ctxb   = (bf16_t*)alloc((size_t)NCTX * CTXD * 2);
  float*  xbuf   = (float*)alloc((size_t)NTOK * DIM * 4);
  bf16_t* lnbuf  = (bf16_t*)alloc((size_t)NTOK * DIM * 2);    // also attention out
  bf16_t* bigbuf = (bf16_t*)alloc((size_t)NTOK * 4096 * 2);   // qkv / ff1 out
  bf16_t* qbuf   = (bf16_t*)alloc((size_t)NTOK * DIM * 2);
  bf16_t* kvbuf  = (bf16_t*)alloc((size_t)NCTX * 2048 * 2);
  if ((size_t)(p - (char*)d_ws) > ws_size) return;  // workspace too small: fail loudly

  dim3 tb(32, 8);
  transpose_to_bf16<<<dim3(3072 / 32, 1024 / 32, NDEPTH), tb, 0, stream>>>(w_qkv, wqkv_t, 1024, 3072);
  transpose_to_bf16<<<dim3(1024 / 32, 1024 / 32, NDEPTH), tb, 0, stream>>>(w_sa_o, wsao_t, 1024, 1024);
  transpose_to_bf16<<<dim3(1024 / 32, 1024 / 32, NDEPTH), tb, 0, stream>>>(w_q, wq_t, 1024, 1024);
  transpose_to_bf16<<<dim3(2048 / 32, 768 / 32, NDEPTH), tb, 0, stream>>>(w_kv, wkv_t, 768, 2048);
  transpose_to_bf16<<<dim3(1024 / 32, 1024 / 32, NDEPTH), tb, 0, stream>>>(w_ca_o, wcao_t, 1024, 1024);
  transpose_to_bf16<<<dim3(4096 / 32, 1024 / 32, NDEPTH), tb, 0, stream>>>(w_ff1, wff1_t, 1024, 4096);
  transpose_to_bf16<<<dim3(1024 / 32, 4096 / 32, NDEPTH), tb, 0, stream>>>(w_ff2, wff2_t, 4096, 1024);
  f32_to_bf16<<<(NCTX * CTXD / 4 + 255) / 256, 256, 0, stream>>>(ctx, ctxb, NCTX * CTXD / 4);
  copy_f32<<<(NTOK * DIM / 4 + 255) / 256, 256, 0, stream>>>(x, xbuf, NTOK * DIM / 4);

  for (int i = 0; i < NDEPTH; ++i) {
    // ---- self-attention ----
    layernorm_f32_bf16<<<NTOK, 256, 0, stream>>>(xbuf, ln1_g + i * DIM, ln1_b + i * DIM, lnbuf);
    gemm_bf16<0><<<dim3(3072 / 128, NTOK / 128), 512, 0, stream>>>(
        lnbuf, wqkv_t + (size_t)i * 3072 * 1024, nullptr, nullptr, bigbuf, NTOK, 3072, 1024);
    attn_fwd<<<dim3(2048 / 128, NHEADS, 2), 512, 0, stream>>>(
        bigbuf, 3072, bigbuf + 1024, bigbuf + 2048, 3072, lnbuf, 1024, 2048, 2048);
    gemm_bf16<3><<<dim3(1024 / 128, NTOK / 128), 512, 0, stream>>>(
        lnbuf, wsao_t + (size_t)i * 1024 * 1024, b_sa_o + i * DIM, xbuf, xbuf, NTOK, 1024, 1024);
    // ---- cross-attention ----
    layernorm_f32_bf16<<<NTOK, 256, 0, stream>>>(xbuf, ln2_g + i * DIM, ln2_b + i * DIM, lnbuf);
    gemm_bf16<0><<<dim3(1024 / 128, NTOK / 128), 512, 0, stream>>>(
        lnbuf, wq_t + (size_t)i * 1024 * 1024, nullptr, nullptr, qbuf, NTOK, 1024, 1024);
    gemm_bf16<0><<<dim3(2048 / 128, NCTX / 128), 512, 0, stream>>>(
        ctxb, wkv_t + (size_t)i * 2048 * 768, nullptr, nullptr, kvbuf, NCTX, 2048, 768);
    attn_fwd<<<dim3(2048 / 128, NHEADS, 2), 512, 0, stream>>>(
        qbuf, 1024, kvbuf, kvbuf + 1024, 2048, lnbuf, 1024, 2048, 1024);
    gemm_bf16<3><<<dim3(1024 / 128, NTOK / 128), 512, 0, stream>>>(
        lnbuf, wcao_t + (size_t)i * 1024 * 1024, b_ca_o + i * DIM, xbuf, xbuf, NTOK, 1024, 1024);
    // ---- feed-forward ----
    layernorm_f32_bf16<<<NTOK, 256, 0, stream>>>(xbuf, ln3_g + i * DIM, ln3_b + i * DIM, lnbuf);
    gemm_bf16<2><<<dim3(4096 / 128, NTOK / 128), 512, 0, stream>>>(
        lnbuf, wff1_t + (size_t)i * 4096 * 1024, b_ff1 + i * MLP_DIM, nullptr, bigbuf, NTOK, 4096, 1024);
    gemm_bf16<3><<<dim3(1024 / 128, NTOK / 128), 512, 0, stream>>>(
        bigbuf, wff2_t + (size_t)i * 1024 * 4096, b_ff2 + i * DIM, xbuf, xbuf, NTOK, 1024, 4096);
  }
  copy_f32<<<(NTOK * DIM / 4 + 255) / 256, 256, 0, stream>>>(xbuf, (float*)d_out, NTOK * DIM / 4);
}

// Round 5
// 1803.201 us; speedup vs baseline: 1.2003x; 1.0337x over previous
//
#include <hip/hip_runtime.h>
#include <hip/hip_bf16.h>
#include <math.h>

typedef __bf16 bf16_t;
typedef __bf16 bf16x8 __attribute__((ext_vector_type(8)));
typedef __bf16 bf16x4 __attribute__((ext_vector_type(4)));
typedef float f32x4 __attribute__((ext_vector_type(4)));
typedef unsigned short u16;
typedef unsigned int u32;
typedef u16 u16x8 __attribute__((ext_vector_type(8)));

#define NDEPTH 4
#define DIM 1024
#define NHEADS 16
#define MLP_DIM 4096
#define CTXD 768
#define NTOK 4096
#define NCTX 2048
#define ATT_SCALE 0.125f

__device__ inline void gload_lds16(const void* g, void* l) {
  __builtin_amdgcn_global_load_lds(
      (const __attribute__((address_space(1))) void*)g,
      (__attribute__((address_space(3))) void*)l, 16, 0, 0);
}

__device__ inline u32 packbf2(float a, float b) {
  union { bf16_t h[2]; u32 w; } u;
  u.h[0] = (bf16_t)a; u.h[1] = (bf16_t)b;
  return u.w;
}

// Shared epilogue: EPI 0 = bf16 out; 2 = bias+GELU bf16; 3 = bias+residual f32.
template<int EPI>
__device__ inline void epi_store(void* outp, const float* bias, const float* res,
                                 int row, int col, int N, float v) {
  size_t idx = (size_t)row * N + col;
  if (EPI == 3) {
    ((float*)outp)[idx] = v + bias[col] + res[idx];
  } else if (EPI == 2) {
    float vb = v + bias[col];
    ((bf16_t*)outp)[idx] = (bf16_t)(0.5f * vb * (1.f + erff(vb * 0.70710678118f)));
  } else {
    ((bf16_t*)outp)[idx] = (bf16_t)v;
  }
}

// ---------------- GEMM 128x128 tile, 512 thr (8 waves 2x4, per-wave 64x32) ----
// 3-buffer LDS pipeline, 2-deep prefetch, counted vmcnt + raw s_barrier.
template<int EPI>
__global__ __launch_bounds__(512) void gemm_bf16(
    const bf16_t* __restrict__ A, const bf16_t* __restrict__ Bt,
    const float* __restrict__ bias, const float* __restrict__ res,
    void* __restrict__ outp, int M, int N, int K)
{
  __shared__ alignas(16) bf16_t As[3][128 * 32];
  __shared__ alignas(16) bf16_t Bs[3][128 * 32];
  const int tid = threadIdx.x, lane = tid & 63, wave = tid >> 6;
  const int bx = blockIdx.x, by = blockIdx.y;
  const int wr = wave >> 2, wc = wave & 3;
  const int l15 = lane & 15, l4 = lane >> 4;

  const bf16_t* Ag = A + (size_t)by * 128 * K;
  const bf16_t* Bg = Bt + (size_t)bx * 128 * K;

  f32x4 acc[4][2] = {};

  const int srow = tid >> 2, soff = (tid & 3) * 8;
  auto stage = [&](int buf, int k0) {
    gload_lds16(Ag + (size_t)srow * K + k0 + soff, &As[buf][(size_t)tid * 8]);
    gload_lds16(Bg + (size_t)srow * K + k0 + soff, &Bs[buf][(size_t)tid * 8]);
  };

  const int nk = K >> 5;
  stage(0, 0);
  stage(1, 32);
  asm volatile("s_waitcnt vmcnt(2)" ::: "memory");
  __builtin_amdgcn_s_barrier();
  __builtin_amdgcn_sched_barrier(0);

  for (int t = 0; t < nk; ++t) {
    const int cur = t % 3;
    if (t + 2 < nk) stage((t + 2) % 3, (t + 2) << 5);

    bf16x8 af[4], bfr[2];
#pragma unroll
    for (int mi = 0; mi < 4; ++mi)
      af[mi] = *(const bf16x8*)&As[cur][(wr * 64 + mi * 16 + l15) * 32 + l4 * 8];
#pragma unroll
    for (int ni = 0; ni < 2; ++ni)
      bfr[ni] = *(const bf16x8*)&Bs[cur][(wc * 32 + ni * 16 + l15) * 32 + l4 * 8];
#pragma unroll
    for (int mi = 0; mi < 4; ++mi)
#pragma unroll
      for (int ni = 0; ni < 2; ++ni)
        acc[mi][ni] = __builtin_amdgcn_mfma_f32_16x16x32_bf16(af[mi], bfr[ni], acc[mi][ni], 0, 0, 0);

    if (t + 2 < nk) {
      asm volatile("s_waitcnt vmcnt(2)" ::: "memory");
    } else if (t + 1 < nk) {
      asm volatile("s_waitcnt vmcnt(0)" ::: "memory");
    } else {
      break;
    }
    __builtin_amdgcn_s_barrier();
    __builtin_amdgcn_sched_barrier(0);
  }

  const int r0 = by * 128 + wr * 64, c0 = bx * 128 + wc * 32;
#pragma unroll
  for (int ni = 0; ni < 2; ++ni)
#pragma unroll
    for (int mi = 0; mi < 4; ++mi)
#pragma unroll
      for (int r = 0; r < 4; ++r)
        epi_store<EPI>(outp, bias, res, r0 + mi * 16 + l4 * 4 + r,
                       c0 + ni * 16 + l15, N, acc[mi][ni][r]);
}

// ---------------- GEMM 64x64 tile, 256 thr (4 waves 2x2, per-wave 32x32) -----
// For grid-starved shapes (N<=2048): 4x the blocks -> 4 blocks/CU, 16 waves/CU,
// cross-block MFMA/VALU overlap (m114) instead of exposed per-iter latency.
template<int EPI>
__global__ __launch_bounds__(256) void gemm64_bf16(
    const bf16_t* __restrict__ A, const bf16_t* __restrict__ Bt,
    const float* __restrict__ bias, const float* __restrict__ res,
    void* __restrict__ outp, int M, int N, int K)
{
  __shared__ alignas(16) bf16_t As[3][64 * 32];
  __shared__ alignas(16) bf16_t Bs[3][64 * 32];
  const int tid = threadIdx.x, lane = tid & 63, wave = tid >> 6;
  const int bx = blockIdx.x, by = blockIdx.y;
  const int wr = wave >> 1, wc = wave & 1;
  const int l15 = lane & 15, l4 = lane >> 4;

  const bf16_t* Ag = A + (size_t)by * 64 * K;
  const bf16_t* Bg = Bt + (size_t)bx * 64 * K;

  f32x4 acc[2][2] = {};

  const int srow = tid >> 2, soff = (tid & 3) * 8;   // 256 thr x 16B = one 64x32 tile
  auto stage = [&](int buf, int k0) {
    gload_lds16(Ag + (size_t)srow * K + k0 + soff, &As[buf][(size_t)tid * 8]);
    gload_lds16(Bg + (size_t)srow * K + k0 + soff, &Bs[buf][(size_t)tid * 8]);
  };

  const int nk = K >> 5;
  stage(0, 0);
  stage(1, 32);
  asm volatile("s_waitcnt vmcnt(2)" ::: "memory");
  __builtin_amdgcn_s_barrier();
  __builtin_amdgcn_sched_barrier(0);

  for (int t = 0; t < nk; ++t) {
    const int cur = t % 3;
    if (t + 2 < nk) stage((t + 2) % 3, (t + 2) << 5);

    bf16x8 af[2], bfr[2];
#pragma unroll
    for (int mi = 0; mi < 2; ++mi)
      af[mi] = *(const bf16x8*)&As[cur][(wr * 32 + mi * 16 + l15) * 32 + l4 * 8];
#pragma unroll
    for (int ni = 0; ni < 2; ++ni)
      bfr[ni] = *(const bf16x8*)&Bs[cur][(wc * 32 + ni * 16 + l15) * 32 + l4 * 8];
#pragma unroll
    for (int mi = 0; mi < 2; ++mi)
#pragma unroll
      for (int ni = 0; ni < 2; ++ni)
        acc[mi][ni] = __builtin_amdgcn_mfma_f32_16x16x32_bf16(af[mi], bfr[ni], acc[mi][ni], 0, 0, 0);

    if (t + 2 < nk) {
      asm volatile("s_waitcnt vmcnt(2)" ::: "memory");
    } else if (t + 1 < nk) {
      asm volatile("s_waitcnt vmcnt(0)" ::: "memory");
    } else {
      break;
    }
    __builtin_amdgcn_s_barrier();
    __builtin_amdgcn_sched_barrier(0);
  }

  const int r0 = by * 64 + wr * 32, c0 = bx * 64 + wc * 32;
#pragma unroll
  for (int ni = 0; ni < 2; ++ni)
#pragma unroll
    for (int mi = 0; mi < 2; ++mi)
#pragma unroll
      for (int r = 0; r < 4; ++r)
        epi_store<EPI>(outp, bias, res, r0 + mi * 16 + l4 * 4 + r,
                       c0 + ni * 16 + l15, N, acc[mi][ni][r]);
}

// ---------------- Flash attention: 128-query tile, 8 waves, d=64 ----------------
// Swapped QK^T; in-register softmax; T13 defer-max; T14 async K/V stage.
__global__ __launch_bounds__(512) void attn_fwd(
    const bf16_t* __restrict__ Q, int qs,
    const bf16_t* __restrict__ K, const bf16_t* __restrict__ V, int kvs,
    bf16_t* __restrict__ O, int os, int nq, int nk)
{
  __shared__ bf16_t Ks[2][64][72];
  __shared__ bf16_t Vt[2][64][72];   // Vt[d][key]

  const int tid = threadIdx.x, lane = tid & 63, wv = tid >> 6;
  const int l15 = lane & 15, l4 = lane >> 4;
  const int h = blockIdx.y, bz = blockIdx.z;
  const size_t qrow0 = (size_t)bz * nq + (size_t)blockIdx.x * 128;
  const bf16_t* Qb = Q + (qrow0 + wv * 16) * qs + h * 64;
  const bf16_t* Kb = K + (size_t)bz * nk * kvs + h * 64;
  const bf16_t* Vb = V + (size_t)bz * nk * kvs + h * 64;
  bf16_t* Ob = O + (qrow0 + wv * 16) * os + h * 64;

  bf16x8 qa[2];
#pragma unroll
  for (int ks = 0; ks < 2; ++ks)
    qa[ks] = *(const bf16x8*)(Qb + (size_t)l15 * qs + ks * 32 + l4 * 8);

  const int krow = tid >> 3, kcol = (tid & 7) * 8;

  u16x8 kreg, vreg;
  auto load_tile = [&](int kt) {
    kreg = *(const u16x8*)(Kb + (size_t)(kt * 64 + krow) * kvs + kcol);
    u16x8 t;
#pragma unroll
    for (int i = 0; i < 8; ++i)
      t[i] = *(const u16*)(Vb + (size_t)(kt * 64 + wv * 8 + i) * kvs + lane);
    vreg = t;
  };
  auto store_tile = [&](int buf) {
    *(u16x8*)&Ks[buf][krow][kcol] = kreg;
    *(u16x8*)&Vt[buf][lane][wv * 8] = vreg;
  };

  float m_run = -1e30f, l_run = 0.f;  // stats for q-row = l15
  f32x4 acc[4] = {};                  // acc[d0][r] = O[q=l4*4+r][d=d0*16+l15]

  const int ntiles = nk >> 6;
  load_tile(0);
  store_tile(0);
  __syncthreads();

  for (int kt = 0; kt < ntiles; ++kt) {
    const int cur = kt & 1;
    const bool pre = (kt + 1 < ntiles);
    if (pre) load_tile(kt + 1);

    // S^T: s[f] holds S[key = f*16 + l4*4 + r][q = l15]
    f32x4 s[4] = {};
#pragma unroll
    for (int ks = 0; ks < 2; ++ks)
#pragma unroll
      for (int f = 0; f < 4; ++f) {
        bf16x8 kf = *(const bf16x8*)&Ks[cur][f * 16 + l15][ks * 32 + l4 * 8];
        s[f] = __builtin_amdgcn_mfma_f32_16x16x32_bf16(kf, qa[ks], s[f], 0, 0, 0);
      }

    float smax = s[0][0];
#pragma unroll
    for (int f = 0; f < 4; ++f)
#pragma unroll
      for (int r = 0; r < 4; ++r) smax = fmaxf(smax, s[f][r]);
    smax = fmaxf(smax, __shfl_xor(smax, 16));
    smax = fmaxf(smax, __shfl_xor(smax, 32));
    smax *= ATT_SCALE;

    // T13 defer-max: skip rescale when no lane's max grew past m_run + 8.
    if (!__all(smax <= m_run + 8.f)) {
      const float mn = fmaxf(m_run, smax);
      const float esc = __expf(m_run - mn);
      m_run = mn;
      l_run *= esc;
#pragma unroll
      for (int r = 0; r < 4; ++r) {
        float eq = __shfl(esc, (l4 << 4) + (l4 << 2) + r);
#pragma unroll
        for (int d0 = 0; d0 < 4; ++d0) acc[d0][r] *= eq;
      }
    }

    float p[4][4], psum = 0.f;
#pragma unroll
    for (int f = 0; f < 4; ++f)
#pragma unroll
      for (int r = 0; r < 4; ++r) {
        float pv = __expf(s[f][r] * ATT_SCALE - m_run);
        p[f][r] = pv;
        psum += pv;
      }
    psum += __shfl_xor(psum, 16);
    psum += __shfl_xor(psum, 32);
    l_run += psum;

    u32 pk[4][2];
#pragma unroll
    for (int f = 0; f < 4; ++f)
#pragma unroll
      for (int hh = 0; hh < 2; ++hh)
        pk[f][hh] = packbf2(p[f][2 * hh], p[f][2 * hh + 1]);

    // redistribute to PV A-fragment: pa[ks] = P[q=l15][key = ks*32 + l4*8 + j]
    bf16x8 pa[2];
#pragma unroll
    for (int ks = 0; ks < 2; ++ks) {
      union { u32 w[4]; bf16x8 v; } pu;
#pragma unroll
      for (int jj = 0; jj < 4; ++jj) {
        int src = l15 + ((((l4 << 1) + (jj >> 1)) & 3) << 4);
        u32 a = (u32)__shfl((int)pk[ks * 2 + 0][jj & 1], src);
        u32 b = (u32)__shfl((int)pk[ks * 2 + 1][jj & 1], src);
        pu.w[jj] = (l4 & 2) ? b : a;
      }
      pa[ks] = pu.v;
    }

#pragma unroll
    for (int ks = 0; ks < 2; ++ks)
#pragma unroll
      for (int d0 = 0; d0 < 4; ++d0) {
        bf16x8 vb = *(const bf16x8*)&Vt[cur][d0 * 16 + l15][ks * 32 + l4 * 8];
        acc[d0] = __builtin_amdgcn_mfma_f32_16x16x32_bf16(pa[ks], vb, acc[d0], 0, 0, 0);
      }

    if (pre) store_tile(cur ^ 1);
    __syncthreads();
  }

#pragma unroll
  for (int r = 0; r < 4; ++r) {
    float lq = __shfl(l_run, (l4 << 4) + (l4 << 2) + r);
    float inv = 1.f / lq;
#pragma unroll
    for (int d0 = 0; d0 < 4; ++d0)
      Ob[(size_t)(l4 * 4 + r) * os + d0 * 16 + l15] = (bf16_t)(acc[d0][r] * inv);
  }
}

// ---------------- LayerNorm: fp32 in, bf16 out, dim=1024 ----------------
__global__ __launch_bounds__(256) void layernorm_f32_bf16(
    const float* __restrict__ x, const float* __restrict__ g, const float* __restrict__ b,
    bf16_t* __restrict__ out)
{
  const int row = blockIdx.x, tid = threadIdx.x;
  const float4 v = ((const float4*)(x + (size_t)row * 1024))[tid];
  float s = v.x + v.y + v.z + v.w;
  float s2 = v.x * v.x + v.y * v.y + v.z * v.z + v.w * v.w;
#pragma unroll
  for (int off = 32; off > 0; off >>= 1) {
    s += __shfl_down(s, off);
    s2 += __shfl_down(s2, off);
  }
  __shared__ float ps[4], ps2[4];
  const int lane = tid & 63, wave = tid >> 6;
  if (lane == 0) { ps[wave] = s; ps2[wave] = s2; }
  __syncthreads();
  s = ps[0] + ps[1] + ps[2] + ps[3];
  s2 = ps2[0] + ps2[1] + ps2[2] + ps2[3];
  const float mu = s * (1.f / 1024.f);
  const float var = s2 * (1.f / 1024.f) - mu * mu;
  const float rstd = rsqrtf(var + 1e-5f);
  const float4 gv = ((const float4*)g)[tid];
  const float4 bv = ((const float4*)b)[tid];
  bf16x4 o;
  o[0] = (bf16_t)((v.x - mu) * rstd * gv.x + bv.x);
  o[1] = (bf16_t)((v.y - mu) * rstd * gv.y + bv.y);
  o[2] = (bf16_t)((v.z - mu) * rstd * gv.z + bv.z);
  o[3] = (bf16_t)((v.w - mu) * rstd * gv.w + bv.w);
  *(bf16x4*)(out + (size_t)row * 1024 + tid * 4) = o;
}

// ---------------- weight transpose fp32[K,N] -> bf16[N,K], per-layer in grid.z ----------------
__global__ void transpose_to_bf16(const float* __restrict__ src, bf16_t* __restrict__ dst, int K, int N)
{
  __shared__ float tile[32][33];
  const size_t loff = (size_t)blockIdx.z * K * N;
  src += loff; dst += loff;
  const int k0 = blockIdx.y * 32, n0 = blockIdx.x * 32;
  const int tx = threadIdx.x, ty = threadIdx.y;
#pragma unroll
  for (int i = ty; i < 32; i += 8)
    tile[i][tx] = src[(size_t)(k0 + i) * N + n0 + tx];
  __syncthreads();
#pragma unroll
  for (int i = ty; i < 32; i += 8)
    dst[(size_t)(n0 + i) * K + k0 + tx] = (bf16_t)tile[tx][i];
}

__global__ void f32_to_bf16(const float* __restrict__ src, bf16_t* __restrict__ dst, int n4)
{
  int i = blockIdx.x * blockDim.x + threadIdx.x;
  if (i < n4) {
    float4 v = ((const float4*)src)[i];
    bf16x4 o;
    o[0] = (bf16_t)v.x; o[1] = (bf16_t)v.y; o[2] = (bf16_t)v.z; o[3] = (bf16_t)v.w;
    ((bf16x4*)dst)[i] = o;
  }
}

__global__ void copy_f32(const float* __restrict__ src, float* __restrict__ dst, int n4)
{
  int i = blockIdx.x * blockDim.x + threadIdx.x;
  if (i < n4) ((float4*)dst)[i] = ((const float4*)src)[i];
}

extern "C" void kernel_launch(void* const* d_in, const int* in_sizes, int n_in,
                              void* d_out, int out_size, void* d_ws, size_t ws_size,
                              hipStream_t stream)
{
  const float* x      = (const float*)d_in[0];
  const float* ctx    = (const float*)d_in[1];
  const float* ln1_g  = (const float*)d_in[2];
  const float* ln1_b  = (const float*)d_in[3];
  const float* w_qkv  = (const float*)d_in[4];
  const float* w_sa_o = (const float*)d_in[5];
  const float* b_sa_o = (const float*)d_in[6];
  const float* ln2_g  = (const float*)d_in[7];
  const float* ln2_b  = (const float*)d_in[8];
  const float* w_q    = (const float*)d_in[9];
  const float* w_kv   = (const float*)d_in[10];
  const float* w_ca_o = (const float*)d_in[11];
  const float* b_ca_o = (const float*)d_in[12];
  const float* ln3_g  = (const float*)d_in[13];
  const float* ln3_b  = (const float*)d_in[14];
  const float* w_ff1  = (const float*)d_in[15];
  const float* b_ff1  = (const float*)d_in[16];
  const float* w_ff2  = (const float*)d_in[17];
  const float* b_ff2  = (const float*)d_in[18];

  char* p = (char*)d_ws;
  auto alloc = [&](size_t bytes) { char* r = p; p += (bytes + 255) & ~(size_t)255; return r; };
  bf16_t* wqkv_t = (bf16_t*)alloc((size_t)NDEPTH * 3072 * 1024 * 2);
  bf16_t* wsao_t = (bf16_t*)alloc((size_t)NDEPTH * 1024 * 1024 * 2);
  bf16_t* wq_t   = (bf16_t*)alloc((size_t)NDEPTH * 1024 * 1024 * 2);
  bf16_t* wkv_t  = (bf16_t*)alloc((size_t)NDEPTH * 2048 * 768 * 2);
  bf16_t* wcao_t = (bf16_t*)alloc((size_t)NDEPTH * 1024 * 1024 * 2);
  bf16_t* wff1_t = (bf16_t*)alloc((size_t)NDEPTH * 4096 * 1024 * 2);
  bf16_t* wff2_t = (bf16_t*)alloc((size_t)NDEPTH * 1024 * 4096 * 2);
  bf16_t* ctxb   = (bf16_t*)alloc((size_t)NCTX * CTXD * 2);
  float*  xbuf   = (float*)alloc((size_t)NTOK * DIM * 4);
  bf16_t* lnbuf  = (bf16_t*)alloc((size_t)NTOK * DIM * 2);    // also attention out
  bf16_t* bigbuf = (bf16_t*)alloc((size_t)NTOK * 4096 * 2);   // qkv / ff1 out
  bf16_t* qbuf   = (bf16_t*)alloc((size_t)NTOK * DIM * 2);
  bf16_t* kvbuf  = (bf16_t*)alloc((size_t)NCTX * 2048 * 2);
  if ((size_t)(p - (char*)d_ws) > ws_size) return;  // workspace too small: fail loudly

  dim3 tb(32, 8);
  transpose_to_bf16<<<dim3(3072 / 32, 1024 / 32, NDEPTH), tb, 0, stream>>>(w_qkv, wqkv_t, 1024, 3072);
  transpose_to_bf16<<<dim3(1024 / 32, 1024 / 32, NDEPTH), tb, 0, stream>>>(w_sa_o, wsao_t, 1024, 1024);
  transpose_to_bf16<<<dim3(1024 / 32, 1024 / 32, NDEPTH), tb, 0, stream>>>(w_q, wq_t, 1024, 1024);
  transpose_to_bf16<<<dim3(2048 / 32, 768 / 32, NDEPTH), tb, 0, stream>>>(w_kv, wkv_t, 768, 2048);
  transpose_to_bf16<<<dim3(1024 / 32, 1024 / 32, NDEPTH), tb, 0, stream>>>(w_ca_o, wcao_t, 1024, 1024);
  transpose_to_bf16<<<dim3(4096 / 32, 1024 / 32, NDEPTH), tb, 0, stream>>>(w_ff1, wff1_t, 1024, 4096);
  transpose_to_bf16<<<dim3(1024 / 32, 4096 / 32, NDEPTH), tb, 0, stream>>>(w_ff2, wff2_t, 4096, 1024);
  f32_to_bf16<<<(NCTX * CTXD / 4 + 255) / 256, 256, 0, stream>>>(ctx, ctxb, NCTX * CTXD / 4);
  copy_f32<<<(NTOK * DIM / 4 + 255) / 256, 256, 0, stream>>>(x, xbuf, NTOK * DIM / 4);

  for (int i = 0; i < NDEPTH; ++i) {
    // ---- self-attention ----
    layernorm_f32_bf16<<<NTOK, 256, 0, stream>>>(xbuf, ln1_g + i * DIM, ln1_b + i * DIM, lnbuf);
    gemm_bf16<0><<<dim3(3072 / 128, NTOK / 128), 512, 0, stream>>>(
        lnbuf, wqkv_t + (size_t)i * 3072 * 1024, nullptr, nullptr, bigbuf, NTOK, 3072, 1024);
    attn_fwd<<<dim3(2048 / 128, NHEADS, 2), 512, 0, stream>>>(
        bigbuf, 3072, bigbuf + 1024, bigbuf + 2048, 3072, lnbuf, 1024, 2048, 2048);
    gemm64_bf16<3><<<dim3(1024 / 64, NTOK / 64), 256, 0, stream>>>(
        lnbuf, wsao_t + (size_t)i * 1024 * 1024, b_sa_o + i * DIM, xbuf, xbuf, NTOK, 1024, 1024);
    // ---- cross-attention ----
    layernorm_f32_bf16<<<NTOK, 256, 0, stream>>>(xbuf, ln2_g + i * DIM, ln2_b + i * DIM, lnbuf);
    gemm64_bf16<0><<<dim3(1024 / 64, NTOK / 64), 256, 0, stream>>>(
        lnbuf, wq_t + (size_t)i * 1024 * 1024, nullptr, nullptr, qbuf, NTOK, 1024, 1024);
    gemm64_bf16<0><<<dim3(2048 / 64, NCTX / 64), 256, 0, stream>>>(
        ctxb, wkv_t + (size_t)i * 2048 * 768, nullptr, nullptr, kvbuf, NCTX, 2048, 768);
    attn_fwd<<<dim3(2048 / 128, NHEADS, 2), 512, 0, stream>>>(
        qbuf, 1024, kvbuf, kvbuf + 1024, 2048, lnbuf, 1024, 2048, 1024);
    gemm64_bf16<3><<<dim3(1024 / 64, NTOK / 64), 256, 0, stream>>>(
        lnbuf, wcao_t + (size_t)i * 1024 * 1024, b_ca_o + i * DIM, xbuf, xbuf, NTOK, 1024, 1024);
    // ---- feed-forward ----
    layernorm_f32_bf16<<<NTOK, 256, 0, stream>>>(xbuf, ln3_g + i * DIM, ln3_b + i * DIM, lnbuf);
    gemm_bf16<2><<<dim3(4096 / 128, NTOK / 128), 512, 0, stream>>>(
        lnbuf, wff1_t + (size_t)i * 4096 * 1024, b_ff1 + i * MLP_DIM, nullptr, bigbuf, NTOK, 4096, 1024);
    gemm64_bf16<3><<<dim3(1024 / 64, NTOK / 64), 256, 0, stream>>>(
        bigbuf, wff2_t + (size_t)i * 1024 * 4096, b_ff2 + i * DIM, xbuf, xbuf, NTOK, 1024, 4096);
  }
  copy_f32<<<(NTOK * DIM / 4 + 255) / 256, 256, 0, stream>>>(xbuf, (float*)d_out, NTOK * DIM / 4);
}